// Round 1
// baseline (3568.562 us; speedup 1.0000x reference)
//
#include <hip/hip_runtime.h>

#define B_    64
#define T_    64
#define V_    32000
#define E_    512
#define H_    1024
#define G4_   4096      // 4*H
#define TS_   63        // time steps actually computed
#define MROWS 4032      // TS_*B_
#define MPAD  4096

typedef __attribute__((ext_vector_type(8))) short bf16x8;   // 8 bf16 = 4 VGPR
typedef __attribute__((ext_vector_type(4))) float f32x4;

__device__ __forceinline__ unsigned short bfbits(float f) {  // fp32 -> bf16 (RNE)
  union { float f; unsigned int u; } cv; cv.f = f;
  unsigned int u = cv.u;
  u += 0x7fffu + ((u >> 16) & 1u);
  return (unsigned short)(u >> 16);
}
__device__ __forceinline__ float bf2f(unsigned short h) {
  union { unsigned int u; float f; } cv; cv.u = ((unsigned int)h) << 16;
  return cv.f;
}

// async global->LDS, 16B per lane (wave-uniform LDS base + lane*16)
__device__ __forceinline__ void gload16(const void* g, void* l) {
  __builtin_amdgcn_global_load_lds(
      (const __attribute__((address_space(1))) unsigned int*)g,
      (__attribute__((address_space(3))) unsigned int*)l, 16, 0, 0);
}

// ---------------- elementwise / init kernels ----------------

__global__ void k_cast4(const float4* __restrict__ s, ushort4* __restrict__ d, int n4) {
  int i = blockIdx.x * blockDim.x + threadIdx.x;
  const int st = gridDim.x * blockDim.x;
  for (; i < n4; i += st) {
    const float4 f = s[i];
    ushort4 v;
    v.x = bfbits(f.x); v.y = bfbits(f.y); v.z = bfbits(f.z); v.w = bfbits(f.w);
    d[i] = v;
  }
}

__global__ void k_bias(const float* __restrict__ a, const float* __restrict__ b,
                       float* __restrict__ o, int n) {
  const int i = blockIdx.x * blockDim.x + threadIdx.x;
  if (i < n) o[i] = a[i] + b[i];
}

// X[m][e] = bf16(embed[captions[b][t]][e]), m = t*64+b (t<63); pad rows -> 0
__global__ void k_gather(const float* __restrict__ embed, const int* __restrict__ caps,
                         unsigned short* __restrict__ X) {
  const int i = blockIdx.x * 256 + threadIdx.x;   // 2048 blocks * 256 = MPAD*E_/4 exact
  const int m = i >> 7, e4 = i & 127;             // 128 float4 per row
  ushort4 v;
  if (m < MROWS) {
    const int t = m >> 6, b = m & 63;
    const int idx = caps[b * T_ + t];
    const float4 f = ((const float4*)embed)[(long)idx * (E_ / 4) + e4];
    v.x = bfbits(f.x); v.y = bfbits(f.y); v.z = bfbits(f.z); v.w = bfbits(f.w);
  } else {
    v = make_ushort4(0, 0, 0, 0);
  }
  ((ushort4*)X)[i] = v;
}

// h0/h1 initial slots (bf16) + private fp32 copies of c0/c1
__global__ void k_init(const float* __restrict__ hidden, const float* __restrict__ cell,
                       unsigned short* __restrict__ H0, unsigned short* __restrict__ H1,
                       float* __restrict__ c0, float* __restrict__ c1) {
  const int i = blockIdx.x * 256 + threadIdx.x;   // 256 blocks -> 65536 = B_*H_ exact
  H0[i] = bfbits(hidden[i]);
  H1[i] = bfbits(hidden[B_ * H_ + i]);
  c0[i] = cell[i];
  c1[i] = cell[B_ * H_ + i];
}

__global__ void k_zeropad(unsigned short* __restrict__ a, unsigned short* __restrict__ b) {
  const int i = blockIdx.x * 256 + threadIdx.x;   // 65536
  a[i] = 0;
  b[i] = 0;
}

__global__ void k_zero_t0(float4* __restrict__ out4) {
  const int i = blockIdx.x * 256 + threadIdx.x;   // 2000 blocks -> 512000 = B_*V_/4 exact
  const int b = i / (V_ / 4), v = i - b * (V_ / 4);
  out4[(long)b * (T_ * V_ / 4) + v] = make_float4(0.f, 0.f, 0.f, 0.f);
}

// ---------------- big GEMM: C(MPADxN) = A(MPADxK) @ Bm(NxK)^T + bias ----------------
// m97 structure: 128x128 tile, BK=32, global_load_lds(16B), 2 barriers/K-step.
// TO_OUT=false: write bf16 C (row-major, stride N). TO_OUT=true: fp32 scatter to logits.
template <int KDIM, bool TO_OUT>
__global__ __launch_bounds__(256) void k_gemm(
    const unsigned short* __restrict__ A, const unsigned short* __restrict__ Bm,
    const float* __restrict__ bias, unsigned short* __restrict__ Cb,
    float* __restrict__ Cout, int N) {
  __shared__ unsigned short As[128 * 32];
  __shared__ unsigned short Bs[128 * 32];
  const int tid = threadIdx.x;
  const int w = tid >> 6, l = tid & 63;
  const int wm = (w >> 1) * 64, wn = (w & 1) * 64;
  const int lr = l & 15, lk = (l >> 4) * 8;
  const long am0 = (long)blockIdx.y * 128;
  const long bn0 = (long)blockIdx.x * 128;

  // staging: A/B tiles are 512 x 16B units each; 2 units/thread/tile
  const int u0 = tid, u1 = tid + 256;
  const char* gA0 = (const char*)(A + (am0 + (u0 >> 2)) * KDIM) + (u0 & 3) * 16;
  const char* gA1 = (const char*)(A + (am0 + (u1 >> 2)) * KDIM) + (u1 & 3) * 16;
  const char* gB0 = (const char*)(Bm + (bn0 + (u0 >> 2)) * KDIM) + (u0 & 3) * 16;
  const char* gB1 = (const char*)(Bm + (bn0 + (u1 >> 2)) * KDIM) + (u1 & 3) * 16;
  char* lA0 = (char*)As + u0 * 16; char* lA1 = (char*)As + u1 * 16;
  char* lB0 = (char*)Bs + u0 * 16; char* lB1 = (char*)Bs + u1 * 16;

  f32x4 acc[4][4];
  const f32x4 z = {0.f, 0.f, 0.f, 0.f};
  #pragma unroll
  for (int mi = 0; mi < 4; ++mi)
    #pragma unroll
    for (int ni = 0; ni < 4; ++ni) acc[mi][ni] = z;

  for (int k0 = 0; k0 < KDIM; k0 += 32) {
    __syncthreads();                       // previous iter's ds_reads done
    gload16(gA0 + (long)k0 * 2, lA0);
    gload16(gA1 + (long)k0 * 2, lA1);
    gload16(gB0 + (long)k0 * 2, lB0);
    gload16(gB1 + (long)k0 * 2, lB1);
    __syncthreads();                       // vmcnt(0) drain -> LDS ready
    bf16x8 af[4], bfr[4];
    #pragma unroll
    for (int mi = 0; mi < 4; ++mi)
      af[mi] = *(const bf16x8*)(As + (wm + mi * 16 + lr) * 32 + lk);
    #pragma unroll
    for (int ni = 0; ni < 4; ++ni)
      bfr[ni] = *(const bf16x8*)(Bs + (wn + ni * 16 + lr) * 32 + lk);
    #pragma unroll
    for (int mi = 0; mi < 4; ++mi)
      #pragma unroll
      for (int ni = 0; ni < 4; ++ni)
        acc[mi][ni] = __builtin_amdgcn_mfma_f32_16x16x32_bf16(af[mi], bfr[ni], acc[mi][ni], 0, 0, 0);
  }

  // epilogue: C/D layout col=lane&15, row=(lane>>4)*4+r
  #pragma unroll
  for (int ni = 0; ni < 4; ++ni) {
    const int n = (int)bn0 + wn + ni * 16 + lr;
    const float bv = bias[n];
    #pragma unroll
    for (int mi = 0; mi < 4; ++mi) {
      #pragma unroll
      for (int r = 0; r < 4; ++r) {
        const int m = (int)am0 + wm + mi * 16 + (l >> 4) * 4 + r;
        const float v = acc[mi][ni][r] + bv;
        if constexpr (TO_OUT) {
          if (m < MROWS) {
            const int t = m >> 6, b = m & 63;
            Cout[(long)(b * T_ + t + 1) * V_ + n] = v;   // logits of step t -> out[:,t+1,:]
          }
        } else {
          Cb[(long)m * N + n] = bfbits(v);
        }
      }
    }
  }
}

// ---------------- recurrent step: gates = In + hin @ W^T, then LSTM cell ----------------
// 64 blocks: block nb owns j-slice jb=nb*16 across all 4 gates (W rows g*1024+jb+jj).
// Wave w computes gate w via register-direct MFMA (A/B tiles L2-resident; no barriers
// in the K-loop -> compiler pipelines the dwordx4 loads).
__global__ __launch_bounds__(256) void k_step(
    const unsigned short* __restrict__ W, const unsigned short* __restrict__ In,
    const unsigned short* __restrict__ hin, unsigned short* __restrict__ hout,
    float* __restrict__ c) {
  __shared__ float gs[4][64][16];
  const int tid = threadIdx.x;
  const int w = tid >> 6, l = tid & 63;
  const int jb = blockIdx.x << 4;
  const int lr = l & 15, lk = (l >> 4) * 8;

  const unsigned short* ap0 = hin + (0 + lr) * H_ + lk;
  const unsigned short* ap1 = hin + (16 + lr) * H_ + lk;
  const unsigned short* ap2 = hin + (32 + lr) * H_ + lk;
  const unsigned short* ap3 = hin + (48 + lr) * H_ + lk;
  const unsigned short* bp  = W + (long)(w * H_ + jb + lr) * H_ + lk;

  f32x4 a0 = {0,0,0,0}, a1 = {0,0,0,0}, a2 = {0,0,0,0}, a3 = {0,0,0,0};
  #pragma unroll 4
  for (int ks = 0; ks < 32; ++ks) {
    const int o = ks * 32;
    const bf16x8 bv = *(const bf16x8*)(bp + o);
    a0 = __builtin_amdgcn_mfma_f32_16x16x32_bf16(*(const bf16x8*)(ap0 + o), bv, a0, 0, 0, 0);
    a1 = __builtin_amdgcn_mfma_f32_16x16x32_bf16(*(const bf16x8*)(ap1 + o), bv, a1, 0, 0, 0);
    a2 = __builtin_amdgcn_mfma_f32_16x16x32_bf16(*(const bf16x8*)(ap2 + o), bv, a2, 0, 0, 0);
    a3 = __builtin_amdgcn_mfma_f32_16x16x32_bf16(*(const bf16x8*)(ap3 + o), bv, a3, 0, 0, 0);
  }
  #pragma unroll
  for (int r = 0; r < 4; ++r) {
    const int br = (l >> 4) * 4 + r;
    gs[w][ 0 + br][lr] = a0[r];
    gs[w][16 + br][lr] = a1[r];
    gs[w][32 + br][lr] = a2[r];
    gs[w][48 + br][lr] = a3[r];
  }
  __syncthreads();
  const int jj = tid & 15;
  #pragma unroll
  for (int i = 0; i < 4; ++i) {
    const int b = (tid >> 4) * 4 + i;
    const unsigned short* inr = In + b * G4_ + jb + jj;
    float gi = gs[0][b][jj] + bf2f(inr[0]);
    float gf = gs[1][b][jj] + bf2f(inr[H_]);
    float gg = gs[2][b][jj] + bf2f(inr[2 * H_]);
    float go = gs[3][b][jj] + bf2f(inr[3 * H_]);
    gi = 1.f / (1.f + __expf(-gi));
    gf = 1.f / (1.f + __expf(-gf));
    go = 1.f / (1.f + __expf(-go));
    gg = tanhf(gg);
    const int ci = b * H_ + jb + jj;
    const float cn = gf * c[ci] + gi * gg;
    c[ci] = cn;
    hout[ci] = bfbits(go * tanhf(cn));
  }
}

// ---------------- launch ----------------

extern "C" void kernel_launch(void* const* d_in, const int* in_sizes, int n_in,
                              void* d_out, int out_size, void* d_ws, size_t ws_size,
                              hipStream_t stream) {
  (void)in_sizes; (void)n_in; (void)out_size; (void)ws_size;
  const float* hidden = (const float*)d_in[0];
  const float* cell   = (const float*)d_in[1];
  const int*   caps   = (const int*)d_in[2];
  const float* embed  = (const float*)d_in[3];
  const float* Wih0   = (const float*)d_in[4];
  const float* Whh0   = (const float*)d_in[5];
  const float* bih0   = (const float*)d_in[6];
  const float* bhh0   = (const float*)d_in[7];
  const float* Wih1   = (const float*)d_in[8];
  const float* Whh1   = (const float*)d_in[9];
  const float* bih1   = (const float*)d_in[10];
  const float* bhh1   = (const float*)d_in[11];
  const float* Wp     = (const float*)d_in[12];
  const float* bp     = (const float*)d_in[13];
  float* out = (float*)d_out;

  // workspace layout (~184 MB)
  char* p = (char*)d_ws;
  auto alloc = [&](size_t bytes) { char* r = p; p += (bytes + 255) & ~(size_t)255; return r; };
  unsigned short* Xbf   = (unsigned short*)alloc((size_t)MPAD * E_ * 2);
  unsigned short* Wih0b = (unsigned short*)alloc((size_t)G4_ * E_ * 2);
  unsigned short* Whh0b = (unsigned short*)alloc((size_t)G4_ * H_ * 2);
  unsigned short* Wih1b = (unsigned short*)alloc((size_t)G4_ * H_ * 2);
  unsigned short* Whh1b = (unsigned short*)alloc((size_t)G4_ * H_ * 2);
  unsigned short* Wpb   = (unsigned short*)alloc((size_t)V_ * H_ * 2);
  unsigned short* Xp    = (unsigned short*)alloc((size_t)MPAD * G4_ * 2);
  unsigned short* Yp    = (unsigned short*)alloc((size_t)MPAD * G4_ * 2);
  unsigned short* H0    = (unsigned short*)alloc((size_t)(MPAD + B_) * H_ * 2);  // slots 0..64 + pad
  unsigned short* H1    = (unsigned short*)alloc((size_t)(MPAD + B_) * H_ * 2);
  float* c0  = (float*)alloc((size_t)B_ * H_ * 4);
  float* c1  = (float*)alloc((size_t)B_ * H_ * 4);
  float* b0s = (float*)alloc((size_t)G4_ * 4);
  float* b1s = (float*)alloc((size_t)G4_ * 4);

  // weight casts fp32 -> bf16
  k_cast4<<<2048, 256, 0, stream>>>((const float4*)Wih0, (ushort4*)Wih0b, G4_ * E_ / 4);
  k_cast4<<<2048, 256, 0, stream>>>((const float4*)Whh0, (ushort4*)Whh0b, G4_ * H_ / 4);
  k_cast4<<<2048, 256, 0, stream>>>((const float4*)Wih1, (ushort4*)Wih1b, G4_ * H_ / 4);
  k_cast4<<<2048, 256, 0, stream>>>((const float4*)Whh1, (ushort4*)Whh1b, G4_ * H_ / 4);
  k_cast4<<<4096, 256, 0, stream>>>((const float4*)Wp,   (ushort4*)Wpb,   V_ * H_ / 4);
  k_bias<<<16, 256, 0, stream>>>(bih0, bhh0, b0s, G4_);
  k_bias<<<16, 256, 0, stream>>>(bih1, bhh1, b1s, G4_);
  k_gather<<<2048, 256, 0, stream>>>(embed, caps, Xbf);
  k_init<<<256, 256, 0, stream>>>(hidden, cell, H0, H1, c0, c1);
  k_zeropad<<<256, 256, 0, stream>>>(H0 + (size_t)MPAD * H_, H1 + (size_t)MPAD * H_);
  k_zero_t0<<<2000, 256, 0, stream>>>((float4*)out);

  // GEMM1: Xp = X @ W_ih0^T + b0   (M=4096, N=4096, K=512)
  k_gemm<512, false><<<dim3(32, 32), 256, 0, stream>>>(Xbf, Wih0b, b0s, Xp, nullptr, G4_);

  // layer-0 recurrence
  for (int t = 0; t < TS_; ++t)
    k_step<<<64, 256, 0, stream>>>(Whh0b, Xp + (size_t)t * B_ * G4_,
                                   H0 + (size_t)t * B_ * H_, H0 + (size_t)(t + 1) * B_ * H_, c0);

  // GEMM2: Yp = H0[1..63] @ W_ih1^T + b1   (M=4096, N=4096, K=1024)
  k_gemm<1024, false><<<dim3(32, 32), 256, 0, stream>>>(H0 + (size_t)B_ * H_, Wih1b, b1s, Yp, nullptr, G4_);

  // layer-1 recurrence
  for (int t = 0; t < TS_; ++t)
    k_step<<<64, 256, 0, stream>>>(Whh1b, Yp + (size_t)t * B_ * G4_,
                                   H1 + (size_t)t * B_ * H_, H1 + (size_t)(t + 1) * B_ * H_, c1);

  // GEMM3: logits = H1[1..63] @ Wp^T + bp -> out[:,1:,:]   (M=4096(4032), N=32000, K=1024)
  k_gemm<1024, true><<<dim3(250, 32), 256, 0, stream>>>(H1 + (size_t)B_ * H_, Wpb, bp, nullptr, out, V_);
}

// Round 2
// 2868.292 us; speedup vs baseline: 1.2441x; 1.2441x over previous
//
#include <hip/hip_runtime.h>

#define B_    64
#define T_    64
#define V_    32000
#define E_    512
#define H_    1024
#define G4_   4096      // 4*H
#define TS_   63        // time steps actually computed
#define MROWS 4032      // TS_*B_
#define MPAD  4096

typedef __attribute__((ext_vector_type(8))) short bf16x8;   // 8 bf16 = 4 VGPR
typedef __attribute__((ext_vector_type(4))) float f32x4;

__device__ __forceinline__ unsigned short bfbits(float f) {  // fp32 -> bf16 (RNE)
  union { float f; unsigned int u; } cv; cv.f = f;
  unsigned int u = cv.u;
  u += 0x7fffu + ((u >> 16) & 1u);
  return (unsigned short)(u >> 16);
}
__device__ __forceinline__ float bf2f(unsigned short h) {
  union { unsigned int u; float f; } cv; cv.u = ((unsigned int)h) << 16;
  return cv.f;
}

// async global->LDS, 16B per lane (wave-uniform LDS base + lane*16)
__device__ __forceinline__ void gload16(const void* g, void* l) {
  __builtin_amdgcn_global_load_lds(
      (const __attribute__((address_space(1))) unsigned int*)g,
      (__attribute__((address_space(3))) unsigned int*)l, 16, 0, 0);
}

// ---------------- elementwise / init kernels ----------------

__global__ void k_cast4(const float4* __restrict__ s, ushort4* __restrict__ d, int n4) {
  int i = blockIdx.x * blockDim.x + threadIdx.x;
  const int st = gridDim.x * blockDim.x;
  for (; i < n4; i += st) {
    const float4 f = s[i];
    ushort4 v;
    v.x = bfbits(f.x); v.y = bfbits(f.y); v.z = bfbits(f.z); v.w = bfbits(f.w);
    d[i] = v;
  }
}

__global__ void k_bias(const float* __restrict__ a, const float* __restrict__ b,
                       float* __restrict__ o, int n) {
  const int i = blockIdx.x * blockDim.x + threadIdx.x;
  if (i < n) o[i] = a[i] + b[i];
}

// X[m][e] = bf16(embed[captions[b][t]][e]), m = t*64+b (t<63); pad rows -> 0
__global__ void k_gather(const float* __restrict__ embed, const int* __restrict__ caps,
                         unsigned short* __restrict__ X) {
  const int i = blockIdx.x * 256 + threadIdx.x;   // 2048 blocks * 256 = MPAD*E_/4 exact
  const int m = i >> 7, e4 = i & 127;             // 128 float4 per row
  ushort4 v;
  if (m < MROWS) {
    const int t = m >> 6, b = m & 63;
    const int idx = caps[b * T_ + t];
    const float4 f = ((const float4*)embed)[(long)idx * (E_ / 4) + e4];
    v.x = bfbits(f.x); v.y = bfbits(f.y); v.z = bfbits(f.z); v.w = bfbits(f.w);
  } else {
    v = make_ushort4(0, 0, 0, 0);
  }
  ((ushort4*)X)[i] = v;
}

// h0/h1 initial slots (bf16) + private fp32 copies of c0/c1 + zero barrier counters
__global__ void k_init(const float* __restrict__ hidden, const float* __restrict__ cell,
                       unsigned short* __restrict__ H0, unsigned short* __restrict__ H1,
                       float* __restrict__ c0, float* __restrict__ c1,
                       unsigned int* __restrict__ cnt) {
  const int i = blockIdx.x * 256 + threadIdx.x;   // 256 blocks -> 65536 = B_*H_ exact
  H0[i] = bfbits(hidden[i]);
  H1[i] = bfbits(hidden[B_ * H_ + i]);
  c0[i] = cell[i];
  c1[i] = cell[B_ * H_ + i];
  if (i < 128) cnt[i] = 0u;
}

__global__ void k_zeropad(unsigned short* __restrict__ a, unsigned short* __restrict__ b) {
  const int i = blockIdx.x * 256 + threadIdx.x;   // 65536
  a[i] = 0;
  b[i] = 0;
}

__global__ void k_zero_t0(float4* __restrict__ out4) {
  const int i = blockIdx.x * 256 + threadIdx.x;   // 2000 blocks -> 512000 = B_*V_/4 exact
  const int b = i / (V_ / 4), v = i - b * (V_ / 4);
  out4[(long)b * (T_ * V_ / 4) + v] = make_float4(0.f, 0.f, 0.f, 0.f);
}

// ---------------- big GEMM: C(MPADxN) = A(MPADxK) @ Bm(NxK)^T + bias ----------------
// m97 structure: 128x128 tile, BK=32, global_load_lds(16B), 2 barriers/K-step.
// TO_OUT=false: write bf16 C (row-major, stride N). TO_OUT=true: fp32 scatter to logits.
template <int KDIM, bool TO_OUT>
__global__ __launch_bounds__(256) void k_gemm(
    const unsigned short* __restrict__ A, const unsigned short* __restrict__ Bm,
    const float* __restrict__ bias, unsigned short* __restrict__ Cb,
    float* __restrict__ Cout, int N) {
  __shared__ unsigned short As[128 * 32];
  __shared__ unsigned short Bs[128 * 32];
  const int tid = threadIdx.x;
  const int w = tid >> 6, l = tid & 63;
  const int wm = (w >> 1) * 64, wn = (w & 1) * 64;
  const int lr = l & 15, lk = (l >> 4) * 8;
  const long am0 = (long)blockIdx.y * 128;
  const long bn0 = (long)blockIdx.x * 128;

  // staging: A/B tiles are 512 x 16B units each; 2 units/thread/tile
  const int u0 = tid, u1 = tid + 256;
  const char* gA0 = (const char*)(A + (am0 + (u0 >> 2)) * KDIM) + (u0 & 3) * 16;
  const char* gA1 = (const char*)(A + (am0 + (u1 >> 2)) * KDIM) + (u1 & 3) * 16;
  const char* gB0 = (const char*)(Bm + (bn0 + (u0 >> 2)) * KDIM) + (u0 & 3) * 16;
  const char* gB1 = (const char*)(Bm + (bn0 + (u1 >> 2)) * KDIM) + (u1 & 3) * 16;
  char* lA0 = (char*)As + u0 * 16; char* lA1 = (char*)As + u1 * 16;
  char* lB0 = (char*)Bs + u0 * 16; char* lB1 = (char*)Bs + u1 * 16;

  f32x4 acc[4][4];
  const f32x4 z = {0.f, 0.f, 0.f, 0.f};
  #pragma unroll
  for (int mi = 0; mi < 4; ++mi)
    #pragma unroll
    for (int ni = 0; ni < 4; ++ni) acc[mi][ni] = z;

  for (int k0 = 0; k0 < KDIM; k0 += 32) {
    __syncthreads();                       // previous iter's ds_reads done
    gload16(gA0 + (long)k0 * 2, lA0);
    gload16(gA1 + (long)k0 * 2, lA1);
    gload16(gB0 + (long)k0 * 2, lB0);
    gload16(gB1 + (long)k0 * 2, lB1);
    __syncthreads();                       // vmcnt(0) drain -> LDS ready
    bf16x8 af[4], bfr[4];
    #pragma unroll
    for (int mi = 0; mi < 4; ++mi)
      af[mi] = *(const bf16x8*)(As + (wm + mi * 16 + lr) * 32 + lk);
    #pragma unroll
    for (int ni = 0; ni < 4; ++ni)
      bfr[ni] = *(const bf16x8*)(Bs + (wn + ni * 16 + lr) * 32 + lk);
    #pragma unroll
    for (int mi = 0; mi < 4; ++mi)
      #pragma unroll
      for (int ni = 0; ni < 4; ++ni)
        acc[mi][ni] = __builtin_amdgcn_mfma_f32_16x16x32_bf16(af[mi], bfr[ni], acc[mi][ni], 0, 0, 0);
  }

  // epilogue: C/D layout col=lane&15, row=(lane>>4)*4+r
  #pragma unroll
  for (int ni = 0; ni < 4; ++ni) {
    const int n = (int)bn0 + wn + ni * 16 + lr;
    const float bv = bias[n];
    #pragma unroll
    for (int mi = 0; mi < 4; ++mi) {
      #pragma unroll
      for (int r = 0; r < 4; ++r) {
        const int m = (int)am0 + wm + mi * 16 + (l >> 4) * 4 + r;
        const float v = acc[mi][ni][r] + bv;
        if constexpr (TO_OUT) {
          if (m < MROWS) {
            const int t = m >> 6, b = m & 63;
            Cout[(long)(b * T_ + t + 1) * V_ + n] = v;   // logits of step t -> out[:,t+1,:]
          }
        } else {
          Cb[(long)m * N + n] = bfbits(v);
        }
      }
    }
  }
}

// ---------------- persistent recurrence: 63 LSTM steps in one kernel ----------------
// 64 blocks (1/CU, co-resident), block nb owns j-slice jb=nb*16 across all 4 gates.
// W_hh slice (64 rows x 1024) staged once in LDS, XOR-swizzled for ds_read_b128.
// Wave w owns batch rows w*16..w*16+15; computes all 4 gates for them -> no LDS
// gate exchange. c-state lives in registers for the whole kernel.
// Inter-step sync: device-scope atomic arrive counter per step + threadfences.
__global__ __launch_bounds__(256) void k_recur(
    const unsigned short* __restrict__ W,    // [4096][1024] bf16
    const unsigned short* __restrict__ In,   // [63][64][4096] bf16 (x-proj + bias)
    unsigned short* __restrict__ Hbuf,       // [64+][64][1024] bf16, slot 0 = init
    const float* __restrict__ cinit,         // [64][1024] fp32
    unsigned int* __restrict__ cnt) {        // [63] zeroed arrive counters
  __shared__ unsigned short Wl[64 * 1024];   // 128 KB
  const int tid = threadIdx.x;
  const int w = tid >> 6, l = tid & 63;
  const int jb = blockIdx.x << 4;
  const int lcol = l & 15, khi = l >> 4;
  const int bw = w * 16;

  // stage W slice: LDS row rr = g*16+jj <- W row g*1024+jb+jj; swizzle 16B unit ^ (jj&7)
  for (int u = tid; u < 64 * 128; u += 256) {
    const int rr = u >> 7, cu = u & 127;
    const int g = rr >> 4, jj = rr & 15;
    const bf16x8 v = *(const bf16x8*)(W + ((size_t)(g * 1024 + jb + jj)) * H_ + cu * 8);
    ((bf16x8*)Wl)[rr * 128 + (cu ^ (jj & 7))] = v;
  }
  // initial cell state in registers
  f32x4 cr;
  #pragma unroll
  for (int r = 0; r < 4; ++r)
    cr[r] = cinit[(size_t)(bw + khi * 4 + r) * H_ + jb + lcol];
  __syncthreads();

  for (int t = 0; t < TS_; ++t) {
    // accumulators init = input projection (+bias), fp32
    const unsigned short* inb = In + (size_t)t * (B_ * G4_);
    f32x4 a0, a1, a2, a3;
    #pragma unroll
    for (int r = 0; r < 4; ++r) {
      const unsigned short* ir = inb + (size_t)(bw + khi * 4 + r) * G4_ + jb + lcol;
      a0[r] = bf2f(ir[0]);
      a1[r] = bf2f(ir[H_]);
      a2[r] = bf2f(ir[2 * H_]);
      a3[r] = bf2f(ir[3 * H_]);
    }
    // gates += hin @ Wslice^T   (A from global, B from LDS)
    const unsigned short* hrow = Hbuf + (size_t)t * (B_ * H_) + (size_t)(bw + lcol) * H_ + khi * 8;
    #pragma unroll 8
    for (int kk = 0; kk < 32; ++kk) {
      const bf16x8 av = *(const bf16x8*)(hrow + kk * 32);
      const bf16x8 b0 = ((const bf16x8*)Wl)[(0 * 16 + lcol) * 128 + ((kk * 4 + khi) ^ (lcol & 7))];
      const bf16x8 b1 = ((const bf16x8*)Wl)[(1 * 16 + lcol) * 128 + ((kk * 4 + khi) ^ (lcol & 7))];
      const bf16x8 b2 = ((const bf16x8*)Wl)[(2 * 16 + lcol) * 128 + ((kk * 4 + khi) ^ (lcol & 7))];
      const bf16x8 b3 = ((const bf16x8*)Wl)[(3 * 16 + lcol) * 128 + ((kk * 4 + khi) ^ (lcol & 7))];
      a0 = __builtin_amdgcn_mfma_f32_16x16x32_bf16(av, b0, a0, 0, 0, 0);
      a1 = __builtin_amdgcn_mfma_f32_16x16x32_bf16(av, b1, a1, 0, 0, 0);
      a2 = __builtin_amdgcn_mfma_f32_16x16x32_bf16(av, b2, a2, 0, 0, 0);
      a3 = __builtin_amdgcn_mfma_f32_16x16x32_bf16(av, b3, a3, 0, 0, 0);
    }
    // LSTM cell update; h -> Hbuf slot t+1
    unsigned short* hop = Hbuf + (size_t)(t + 1) * (B_ * H_);
    #pragma unroll
    for (int r = 0; r < 4; ++r) {
      const float gi = 1.f / (1.f + __expf(-a0[r]));
      const float gf = 1.f / (1.f + __expf(-a1[r]));
      const float gg = tanhf(a2[r]);
      const float go = 1.f / (1.f + __expf(-a3[r]));
      cr[r] = gf * cr[r] + gi * gg;
      hop[(size_t)(bw + khi * 4 + r) * H_ + jb + lcol] = bfbits(go * tanhf(cr[r]));
    }
    // inter-block step barrier (skip after last step)
    if (t < TS_ - 1) {
      __threadfence();            // release: push h stores past non-coherent L2
      __syncthreads();
      if (tid == 0) {
        atomicAdd(&cnt[t], 1u);
        while (__hip_atomic_load(&cnt[t], __ATOMIC_ACQUIRE, __HIP_MEMORY_SCOPE_AGENT) < 64u)
          __builtin_amdgcn_s_sleep(2);
      }
      __syncthreads();
      __threadfence();            // acquire: invalidate stale lines before reading new h
    }
  }
}

// ---------------- launch ----------------

extern "C" void kernel_launch(void* const* d_in, const int* in_sizes, int n_in,
                              void* d_out, int out_size, void* d_ws, size_t ws_size,
                              hipStream_t stream) {
  (void)in_sizes; (void)n_in; (void)out_size; (void)ws_size;
  const float* hidden = (const float*)d_in[0];
  const float* cell   = (const float*)d_in[1];
  const int*   caps   = (const int*)d_in[2];
  const float* embed  = (const float*)d_in[3];
  const float* Wih0   = (const float*)d_in[4];
  const float* Whh0   = (const float*)d_in[5];
  const float* bih0   = (const float*)d_in[6];
  const float* bhh0   = (const float*)d_in[7];
  const float* Wih1   = (const float*)d_in[8];
  const float* Whh1   = (const float*)d_in[9];
  const float* bih1   = (const float*)d_in[10];
  const float* bhh1   = (const float*)d_in[11];
  const float* Wp     = (const float*)d_in[12];
  const float* bp     = (const float*)d_in[13];
  float* out = (float*)d_out;

  // workspace layout (~240 MB)
  char* p = (char*)d_ws;
  auto alloc = [&](size_t bytes) { char* r = p; p += (bytes + 255) & ~(size_t)255; return r; };
  unsigned short* Xbf   = (unsigned short*)alloc((size_t)MPAD * E_ * 2);
  unsigned short* Wih0b = (unsigned short*)alloc((size_t)G4_ * E_ * 2);
  unsigned short* Whh0b = (unsigned short*)alloc((size_t)G4_ * H_ * 2);
  unsigned short* Wih1b = (unsigned short*)alloc((size_t)G4_ * H_ * 2);
  unsigned short* Whh1b = (unsigned short*)alloc((size_t)G4_ * H_ * 2);
  unsigned short* Wpb   = (unsigned short*)alloc((size_t)V_ * H_ * 2);
  unsigned short* Xp    = (unsigned short*)alloc((size_t)MPAD * G4_ * 2);
  unsigned short* Yp    = (unsigned short*)alloc((size_t)MPAD * G4_ * 2);
  unsigned short* H0    = (unsigned short*)alloc((size_t)(MPAD + B_) * H_ * 2);  // slots 0..64 + pad
  unsigned short* H1    = (unsigned short*)alloc((size_t)(MPAD + B_) * H_ * 2);
  float* c0  = (float*)alloc((size_t)B_ * H_ * 4);
  float* c1  = (float*)alloc((size_t)B_ * H_ * 4);
  float* b0s = (float*)alloc((size_t)G4_ * 4);
  float* b1s = (float*)alloc((size_t)G4_ * 4);
  unsigned int* cbar = (unsigned int*)alloc(128 * 4);

  // weight casts fp32 -> bf16
  k_cast4<<<2048, 256, 0, stream>>>((const float4*)Wih0, (ushort4*)Wih0b, G4_ * E_ / 4);
  k_cast4<<<2048, 256, 0, stream>>>((const float4*)Whh0, (ushort4*)Whh0b, G4_ * H_ / 4);
  k_cast4<<<2048, 256, 0, stream>>>((const float4*)Wih1, (ushort4*)Wih1b, G4_ * H_ / 4);
  k_cast4<<<2048, 256, 0, stream>>>((const float4*)Whh1, (ushort4*)Whh1b, G4_ * H_ / 4);
  k_cast4<<<4096, 256, 0, stream>>>((const float4*)Wp,   (ushort4*)Wpb,   V_ * H_ / 4);
  k_bias<<<16, 256, 0, stream>>>(bih0, bhh0, b0s, G4_);
  k_bias<<<16, 256, 0, stream>>>(bih1, bhh1, b1s, G4_);
  k_gather<<<2048, 256, 0, stream>>>(embed, caps, Xbf);
  k_init<<<256, 256, 0, stream>>>(hidden, cell, H0, H1, c0, c1, cbar);
  k_zeropad<<<256, 256, 0, stream>>>(H0 + (size_t)MPAD * H_, H1 + (size_t)MPAD * H_);
  k_zero_t0<<<2000, 256, 0, stream>>>((float4*)out);

  // GEMM1: Xp = X @ W_ih0^T + b0   (M=4096, N=4096, K=512)
  k_gemm<512, false><<<dim3(32, 32), 256, 0, stream>>>(Xbf, Wih0b, b0s, Xp, nullptr, G4_);

  // layer-0 recurrence: all 63 steps in one persistent kernel
  k_recur<<<64, 256, 0, stream>>>(Whh0b, Xp, H0, c0, cbar);

  // GEMM2: Yp = H0[1..63] @ W_ih1^T + b1   (M=4096, N=4096, K=1024)
  k_gemm<1024, false><<<dim3(32, 32), 256, 0, stream>>>(H0 + (size_t)B_ * H_, Wih1b, b1s, Yp, nullptr, G4_);

  // layer-1 recurrence
  k_recur<<<64, 256, 0, stream>>>(Whh1b, Yp, H1, c1, cbar + 64);

  // GEMM3: logits = H1[1..63] @ Wp^T + bp -> out[:,1:,:]   (M=4096(4032), N=32000, K=1024)
  k_gemm<1024, true><<<dim3(250, 32), 256, 0, stream>>>(H1 + (size_t)B_ * H_, Wpb, bp, nullptr, out, V_);
}

// Round 3
// 1990.717 us; speedup vs baseline: 1.7926x; 1.4408x over previous
//
#include <hip/hip_runtime.h>

#define B_    64
#define T_    64
#define V_    32000
#define E_    512
#define H_    1024
#define G4_   4096      // 4*H
#define TS_   63        // time steps actually computed
#define MROWS 4032      // TS_*B_
#define MPAD  4096

typedef __attribute__((ext_vector_type(8))) short bf16x8;   // 8 bf16 = 4 VGPR
typedef __attribute__((ext_vector_type(4))) float f32x4;

__device__ __forceinline__ unsigned short bfbits(float f) {  // fp32 -> bf16 (RNE)
  union { float f; unsigned int u; } cv; cv.f = f;
  unsigned int u = cv.u;
  u += 0x7fffu + ((u >> 16) & 1u);
  return (unsigned short)(u >> 16);
}
__device__ __forceinline__ float bf2f(unsigned short h) {
  union { unsigned int u; float f; } cv; cv.u = ((unsigned int)h) << 16;
  return cv.f;
}

// async global->LDS, 16B per lane (wave-uniform LDS base + lane*16)
__device__ __forceinline__ void gload16(const void* g, void* l) {
  __builtin_amdgcn_global_load_lds(
      (const __attribute__((address_space(1))) unsigned int*)g,
      (__attribute__((address_space(3))) unsigned int*)l, 16, 0, 0);
}

// ---------------- elementwise / init kernels ----------------

__global__ void k_cast4(const float4* __restrict__ s, ushort4* __restrict__ d, int n4) {
  int i = blockIdx.x * blockDim.x + threadIdx.x;
  const int st = gridDim.x * blockDim.x;
  for (; i < n4; i += st) {
    const float4 f = s[i];
    ushort4 v;
    v.x = bfbits(f.x); v.y = bfbits(f.y); v.z = bfbits(f.z); v.w = bfbits(f.w);
    d[i] = v;
  }
}

__global__ void k_bias(const float* __restrict__ a, const float* __restrict__ b,
                       float* __restrict__ o, int n) {
  const int i = blockIdx.x * blockDim.x + threadIdx.x;
  if (i < n) o[i] = a[i] + b[i];
}

// X[m][e] = bf16(embed[captions[b][t]][e]), m = t*64+b (t<63); pad rows -> 0
__global__ void k_gather(const float* __restrict__ embed, const int* __restrict__ caps,
                         unsigned short* __restrict__ X) {
  const int i = blockIdx.x * 256 + threadIdx.x;   // 2048 blocks * 256 = MPAD*E_/4 exact
  const int m = i >> 7, e4 = i & 127;             // 128 float4 per row
  ushort4 v;
  if (m < MROWS) {
    const int t = m >> 6, b = m & 63;
    const int idx = caps[b * T_ + t];
    const float4 f = ((const float4*)embed)[(long)idx * (E_ / 4) + e4];
    v.x = bfbits(f.x); v.y = bfbits(f.y); v.z = bfbits(f.z); v.w = bfbits(f.w);
  } else {
    v = make_ushort4(0, 0, 0, 0);
  }
  ((ushort4*)X)[i] = v;
}

// h0/h1 initial slots (bf16) + private fp32 copies of c0/c1 + zero barrier counters
__global__ void k_init(const float* __restrict__ hidden, const float* __restrict__ cell,
                       unsigned short* __restrict__ H0, unsigned short* __restrict__ H1,
                       float* __restrict__ c0, float* __restrict__ c1,
                       unsigned int* __restrict__ cnt) {
  const int i = blockIdx.x * 256 + threadIdx.x;   // 256 blocks -> 65536 = B_*H_ exact
  H0[i] = bfbits(hidden[i]);
  H1[i] = bfbits(hidden[B_ * H_ + i]);
  c0[i] = cell[i];
  c1[i] = cell[B_ * H_ + i];
  if (i < 128) cnt[i] = 0u;
}

__global__ void k_zeropad(unsigned short* __restrict__ a, unsigned short* __restrict__ b) {
  const int i = blockIdx.x * 256 + threadIdx.x;   // 65536
  a[i] = 0;
  b[i] = 0;
}

__global__ void k_zero_t0(float4* __restrict__ out4) {
  const int i = blockIdx.x * 256 + threadIdx.x;   // 2000 blocks -> 512000 = B_*V_/4 exact
  const int b = i / (V_ / 4), v = i - b * (V_ / 4);
  out4[(long)b * (T_ * V_ / 4) + v] = make_float4(0.f, 0.f, 0.f, 0.f);
}

// ---------------- big GEMM: C(MPADxN) = A(MPADxK) @ Bm(NxK)^T + bias ----------------
// m97 structure: 128x128 tile, BK=32, global_load_lds(16B), 2 barriers/K-step.
// TO_OUT=false: write bf16 C (row-major, stride N). TO_OUT=true: fp32 scatter to logits.
template <int KDIM, bool TO_OUT>
__global__ __launch_bounds__(256) void k_gemm(
    const unsigned short* __restrict__ A, const unsigned short* __restrict__ Bm,
    const float* __restrict__ bias, unsigned short* __restrict__ Cb,
    float* __restrict__ Cout, int N) {
  __shared__ unsigned short As[128 * 32];
  __shared__ unsigned short Bs[128 * 32];
  const int tid = threadIdx.x;
  const int w = tid >> 6, l = tid & 63;
  const int wm = (w >> 1) * 64, wn = (w & 1) * 64;
  const int lr = l & 15, lk = (l >> 4) * 8;
  const long am0 = (long)blockIdx.y * 128;
  const long bn0 = (long)blockIdx.x * 128;

  // staging: A/B tiles are 512 x 16B units each; 2 units/thread/tile
  const int u0 = tid, u1 = tid + 256;
  const char* gA0 = (const char*)(A + (am0 + (u0 >> 2)) * KDIM) + (u0 & 3) * 16;
  const char* gA1 = (const char*)(A + (am0 + (u1 >> 2)) * KDIM) + (u1 & 3) * 16;
  const char* gB0 = (const char*)(Bm + (bn0 + (u0 >> 2)) * KDIM) + (u0 & 3) * 16;
  const char* gB1 = (const char*)(Bm + (bn0 + (u1 >> 2)) * KDIM) + (u1 & 3) * 16;
  char* lA0 = (char*)As + u0 * 16; char* lA1 = (char*)As + u1 * 16;
  char* lB0 = (char*)Bs + u0 * 16; char* lB1 = (char*)Bs + u1 * 16;

  f32x4 acc[4][4];
  const f32x4 z = {0.f, 0.f, 0.f, 0.f};
  #pragma unroll
  for (int mi = 0; mi < 4; ++mi)
    #pragma unroll
    for (int ni = 0; ni < 4; ++ni) acc[mi][ni] = z;

  for (int k0 = 0; k0 < KDIM; k0 += 32) {
    __syncthreads();                       // previous iter's ds_reads done
    gload16(gA0 + (long)k0 * 2, lA0);
    gload16(gA1 + (long)k0 * 2, lA1);
    gload16(gB0 + (long)k0 * 2, lB0);
    gload16(gB1 + (long)k0 * 2, lB1);
    __syncthreads();                       // vmcnt(0) drain -> LDS ready
    bf16x8 af[4], bfr[4];
    #pragma unroll
    for (int mi = 0; mi < 4; ++mi)
      af[mi] = *(const bf16x8*)(As + (wm + mi * 16 + lr) * 32 + lk);
    #pragma unroll
    for (int ni = 0; ni < 4; ++ni)
      bfr[ni] = *(const bf16x8*)(Bs + (wn + ni * 16 + lr) * 32 + lk);
    #pragma unroll
    for (int mi = 0; mi < 4; ++mi)
      #pragma unroll
      for (int ni = 0; ni < 4; ++ni)
        acc[mi][ni] = __builtin_amdgcn_mfma_f32_16x16x32_bf16(af[mi], bfr[ni], acc[mi][ni], 0, 0, 0);
  }

  // epilogue: C/D layout col=lane&15, row=(lane>>4)*4+r
  #pragma unroll
  for (int ni = 0; ni < 4; ++ni) {
    const int n = (int)bn0 + wn + ni * 16 + lr;
    const float bv = bias[n];
    #pragma unroll
    for (int mi = 0; mi < 4; ++mi) {
      #pragma unroll
      for (int r = 0; r < 4; ++r) {
        const int m = (int)am0 + wm + mi * 16 + (l >> 4) * 4 + r;
        const float v = acc[mi][ni][r] + bv;
        if constexpr (TO_OUT) {
          if (m < MROWS) {
            const int t = m >> 6, b = m & 63;
            Cout[(long)(b * T_ + t + 1) * V_ + n] = v;   // logits of step t -> out[:,t+1,:]
          }
        } else {
          Cb[(long)m * N + n] = bfbits(v);
        }
      }
    }
  }
}

// ---------------- persistent recurrence: 63 LSTM steps in one kernel ----------------
// 64 blocks (1/CU, co-resident), block nb owns j-slice jb=nb*16 across all 4 gates.
// W_hh slice staged once in LDS (XOR-swizzled). Wave w owns batch rows w*16..+15,
// computes all 4 gates; c-state in registers. Inter-step sync: RELAXED-poll arrive
// counter + minimal release(wbl2)/acquire(inv) fence pair — NOT per-poll invalidates.
// In[t+1] is prefetched into registers before the barrier (read-only data, regs
// survive the L2 invalidate) so only the h-load is on the post-barrier path.
__global__ __launch_bounds__(256) void k_recur(
    const unsigned short* __restrict__ W,    // [4096][1024] bf16
    const unsigned short* __restrict__ In,   // [63][64][4096] bf16 (x-proj + bias)
    unsigned short* __restrict__ Hbuf,       // [64+][64][1024] bf16, slot 0 = init
    const float* __restrict__ cinit,         // [64][1024] fp32
    unsigned int* __restrict__ cnt) {        // [64] zeroed arrive counters
  __shared__ unsigned short Wl[64 * 1024];   // 128 KB
  const int tid = threadIdx.x;
  const int w = tid >> 6, l = tid & 63;
  const int jb = blockIdx.x << 4;
  const int lcol = l & 15, khi = l >> 4;
  const int bw = w * 16;

  // stage W slice: LDS row rr = g*16+jj <- W row g*1024+jb+jj; swizzle 16B unit ^ (jj&7)
  for (int u = tid; u < 64 * 128; u += 256) {
    const int rr = u >> 7, cu = u & 127;
    const int g = rr >> 4, jj = rr & 15;
    const bf16x8 v = *(const bf16x8*)(W + ((size_t)(g * 1024 + jb + jj)) * H_ + cu * 8);
    ((bf16x8*)Wl)[rr * 128 + (cu ^ (jj & 7))] = v;
  }
  // initial cell state in registers
  f32x4 cr;
  #pragma unroll
  for (int r = 0; r < 4; ++r)
    cr[r] = cinit[(size_t)(bw + khi * 4 + r) * H_ + jb + lcol];

  // prefetch In[0] into registers (static indexing -> stays in VGPRs)
  unsigned short pin[16];
  #pragma unroll
  for (int r = 0; r < 4; ++r) {
    const unsigned short* ir = In + (size_t)(bw + khi * 4 + r) * G4_ + jb + lcol;
    pin[r * 4 + 0] = ir[0];
    pin[r * 4 + 1] = ir[H_];
    pin[r * 4 + 2] = ir[2 * H_];
    pin[r * 4 + 3] = ir[3 * H_];
  }
  __syncthreads();

  for (int t = 0; t < TS_; ++t) {
    // accumulators init = prefetched input projection (+bias), fp32
    f32x4 a0, a1, a2, a3;
    #pragma unroll
    for (int r = 0; r < 4; ++r) {
      a0[r] = bf2f(pin[r * 4 + 0]);
      a1[r] = bf2f(pin[r * 4 + 1]);
      a2[r] = bf2f(pin[r * 4 + 2]);
      a3[r] = bf2f(pin[r * 4 + 3]);
    }
    // gates += hin @ Wslice^T   (A from global, B from LDS)
    const unsigned short* hrow = Hbuf + (size_t)t * (B_ * H_) + (size_t)(bw + lcol) * H_ + khi * 8;
    #pragma unroll 8
    for (int kk = 0; kk < 32; ++kk) {
      const bf16x8 av = *(const bf16x8*)(hrow + kk * 32);
      const bf16x8 b0 = ((const bf16x8*)Wl)[(0 * 16 + lcol) * 128 + ((kk * 4 + khi) ^ (lcol & 7))];
      const bf16x8 b1 = ((const bf16x8*)Wl)[(1 * 16 + lcol) * 128 + ((kk * 4 + khi) ^ (lcol & 7))];
      const bf16x8 b2 = ((const bf16x8*)Wl)[(2 * 16 + lcol) * 128 + ((kk * 4 + khi) ^ (lcol & 7))];
      const bf16x8 b3 = ((const bf16x8*)Wl)[(3 * 16 + lcol) * 128 + ((kk * 4 + khi) ^ (lcol & 7))];
      a0 = __builtin_amdgcn_mfma_f32_16x16x32_bf16(av, b0, a0, 0, 0, 0);
      a1 = __builtin_amdgcn_mfma_f32_16x16x32_bf16(av, b1, a1, 0, 0, 0);
      a2 = __builtin_amdgcn_mfma_f32_16x16x32_bf16(av, b2, a2, 0, 0, 0);
      a3 = __builtin_amdgcn_mfma_f32_16x16x32_bf16(av, b3, a3, 0, 0, 0);
    }
    // LSTM cell update; h -> Hbuf slot t+1
    unsigned short* hop = Hbuf + (size_t)(t + 1) * (B_ * H_);
    #pragma unroll
    for (int r = 0; r < 4; ++r) {
      const float gi = 1.f / (1.f + __expf(-a0[r]));
      const float gf = 1.f / (1.f + __expf(-a1[r]));
      const float gg = tanhf(a2[r]);
      const float go = 1.f / (1.f + __expf(-a3[r]));
      cr[r] = gf * cr[r] + gi * gg;
      hop[(size_t)(bw + khi * 4 + r) * H_ + jb + lcol] = bfbits(go * tanhf(cr[r]));
    }
    // prefetch In[t+1] before the barrier (independent of it; drains with h stores)
    if (t + 1 < TS_) {
      const unsigned short* inb = In + (size_t)(t + 1) * (B_ * G4_);
      #pragma unroll
      for (int r = 0; r < 4; ++r) {
        const unsigned short* ir = inb + (size_t)(bw + khi * 4 + r) * G4_ + jb + lcol;
        pin[r * 4 + 0] = ir[0];
        pin[r * 4 + 1] = ir[H_];
        pin[r * 4 + 2] = ir[2 * H_];
        pin[r * 4 + 3] = ir[3 * H_];
      }
    }
    // inter-block step barrier (skip after last step)
    if (t < TS_ - 1) {
      __syncthreads();   // per-wave vmcnt(0) drain: all h stores are in L2
      if (tid == 0) {
        __builtin_amdgcn_fence(__ATOMIC_RELEASE, "agent");   // wbl2: L2 -> coherence point
        __hip_atomic_fetch_add(&cnt[t], 1u, __ATOMIC_RELAXED, __HIP_MEMORY_SCOPE_AGENT);
        while (__hip_atomic_load(&cnt[t], __ATOMIC_RELAXED, __HIP_MEMORY_SCOPE_AGENT) < 64u) {
        }
        __builtin_amdgcn_fence(__ATOMIC_ACQUIRE, "agent");   // single inv after wait
      }
      __syncthreads();
    }
  }
}

// ---------------- launch ----------------

extern "C" void kernel_launch(void* const* d_in, const int* in_sizes, int n_in,
                              void* d_out, int out_size, void* d_ws, size_t ws_size,
                              hipStream_t stream) {
  (void)in_sizes; (void)n_in; (void)out_size; (void)ws_size;
  const float* hidden = (const float*)d_in[0];
  const float* cell   = (const float*)d_in[1];
  const int*   caps   = (const int*)d_in[2];
  const float* embed  = (const float*)d_in[3];
  const float* Wih0   = (const float*)d_in[4];
  const float* Whh0   = (const float*)d_in[5];
  const float* bih0   = (const float*)d_in[6];
  const float* bhh0   = (const float*)d_in[7];
  const float* Wih1   = (const float*)d_in[8];
  const float* Whh1   = (const float*)d_in[9];
  const float* bih1   = (const float*)d_in[10];
  const float* bhh1   = (const float*)d_in[11];
  const float* Wp     = (const float*)d_in[12];
  const float* bp     = (const float*)d_in[13];
  float* out = (float*)d_out;

  // workspace layout (~240 MB)
  char* p = (char*)d_ws;
  auto alloc = [&](size_t bytes) { char* r = p; p += (bytes + 255) & ~(size_t)255; return r; };
  unsigned short* Xbf   = (unsigned short*)alloc((size_t)MPAD * E_ * 2);
  unsigned short* Wih0b = (unsigned short*)alloc((size_t)G4_ * E_ * 2);
  unsigned short* Whh0b = (unsigned short*)alloc((size_t)G4_ * H_ * 2);
  unsigned short* Wih1b = (unsigned short*)alloc((size_t)G4_ * H_ * 2);
  unsigned short* Whh1b = (unsigned short*)alloc((size_t)G4_ * H_ * 2);
  unsigned short* Wpb   = (unsigned short*)alloc((size_t)V_ * H_ * 2);
  unsigned short* Xp    = (unsigned short*)alloc((size_t)MPAD * G4_ * 2);
  unsigned short* Yp    = (unsigned short*)alloc((size_t)MPAD * G4_ * 2);
  unsigned short* H0    = (unsigned short*)alloc((size_t)(MPAD + B_) * H_ * 2);  // slots 0..64 + pad
  unsigned short* H1    = (unsigned short*)alloc((size_t)(MPAD + B_) * H_ * 2);
  float* c0  = (float*)alloc((size_t)B_ * H_ * 4);
  float* c1  = (float*)alloc((size_t)B_ * H_ * 4);
  float* b0s = (float*)alloc((size_t)G4_ * 4);
  float* b1s = (float*)alloc((size_t)G4_ * 4);
  unsigned int* cbar = (unsigned int*)alloc(128 * 4);

  // weight casts fp32 -> bf16
  k_cast4<<<2048, 256, 0, stream>>>((const float4*)Wih0, (ushort4*)Wih0b, G4_ * E_ / 4);
  k_cast4<<<2048, 256, 0, stream>>>((const float4*)Whh0, (ushort4*)Whh0b, G4_ * H_ / 4);
  k_cast4<<<2048, 256, 0, stream>>>((const float4*)Wih1, (ushort4*)Wih1b, G4_ * H_ / 4);
  k_cast4<<<2048, 256, 0, stream>>>((const float4*)Whh1, (ushort4*)Whh1b, G4_ * H_ / 4);
  k_cast4<<<4096, 256, 0, stream>>>((const float4*)Wp,   (ushort4*)Wpb,   V_ * H_ / 4);
  k_bias<<<16, 256, 0, stream>>>(bih0, bhh0, b0s, G4_);
  k_bias<<<16, 256, 0, stream>>>(bih1, bhh1, b1s, G4_);
  k_gather<<<2048, 256, 0, stream>>>(embed, caps, Xbf);
  k_init<<<256, 256, 0, stream>>>(hidden, cell, H0, H1, c0, c1, cbar);
  k_zeropad<<<256, 256, 0, stream>>>(H0 + (size_t)MPAD * H_, H1 + (size_t)MPAD * H_);
  k_zero_t0<<<2000, 256, 0, stream>>>((float4*)out);

  // GEMM1: Xp = X @ W_ih0^T + b0   (M=4096, N=4096, K=512)
  k_gemm<512, false><<<dim3(32, 32), 256, 0, stream>>>(Xbf, Wih0b, b0s, Xp, nullptr, G4_);

  // layer-0 recurrence: all 63 steps in one persistent kernel
  k_recur<<<64, 256, 0, stream>>>(Whh0b, Xp, H0, c0, cbar);

  // GEMM2: Yp = H0[1..63] @ W_ih1^T + b1   (M=4096, N=4096, K=1024)
  k_gemm<1024, false><<<dim3(32, 32), 256, 0, stream>>>(H0 + (size_t)B_ * H_, Wih1b, b1s, Yp, nullptr, G4_);

  // layer-1 recurrence
  k_recur<<<64, 256, 0, stream>>>(Whh1b, Yp, H1, c1, cbar + 64);

  // GEMM3: logits = H1[1..63] @ Wp^T + bp -> out[:,1:,:]   (M=4096(4032), N=32000, K=1024)
  k_gemm<1024, true><<<dim3(250, 32), 256, 0, stream>>>(H1 + (size_t)B_ * H_, Wpb, bp, nullptr, out, V_);
}

// Round 4
// 1825.503 us; speedup vs baseline: 1.9548x; 1.0905x over previous
//
#include <hip/hip_runtime.h>

#define B_    64
#define T_    64
#define V_    32000
#define E_    512
#define H_    1024
#define G4_   4096      // 4*H
#define TS_   63        // time steps actually computed
#define MROWS 4032      // TS_*B_
#define MPAD  4096

typedef __attribute__((ext_vector_type(8))) short bf16x8;   // 8 bf16 = 4 VGPR
typedef __attribute__((ext_vector_type(4))) float f32x4;

__device__ __forceinline__ unsigned short bfbits(float f) {  // fp32 -> bf16 (RNE)
  union { float f; unsigned int u; } cv; cv.f = f;
  unsigned int u = cv.u;
  u += 0x7fffu + ((u >> 16) & 1u);
  return (unsigned short)(u >> 16);
}
__device__ __forceinline__ float bf2f(unsigned short h) {
  union { unsigned int u; float f; } cv; cv.u = ((unsigned int)h) << 16;
  return cv.f;
}

// ---- device-coherent (sc0 sc1) accesses: write-through to / read from the
// ---- device coherence point, bypassing the non-coherent per-XCD L2.
__device__ __forceinline__ void store_short_dc(void* p, unsigned short v) {
  unsigned int vv = v;
  asm volatile("global_store_short %0, %1, off sc0 sc1" :: "v"(p), "v"(vv) : "memory");
}
__device__ __forceinline__ void store_dword_dc(void* p, unsigned int v) {
  asm volatile("global_store_dword %0, %1, off sc0 sc1" :: "v"(p), "v"(v) : "memory");
}
__device__ __forceinline__ unsigned int load_dword_dc(const void* p) {
  unsigned int v;
  asm volatile("global_load_dword %0, %1, off sc0 sc1\n\ts_waitcnt vmcnt(0)"
               : "=v"(v) : "v"(p) : "memory");
  return v;
}

// async global->LDS, 16B per lane (wave-uniform LDS base + lane*16)
__device__ __forceinline__ void gload16(const void* g, void* l) {
  __builtin_amdgcn_global_load_lds(
      (const __attribute__((address_space(1))) unsigned int*)g,
      (__attribute__((address_space(3))) unsigned int*)l, 16, 0, 0);
}

// ---------------- elementwise / init kernels ----------------

__global__ void k_cast4(const float4* __restrict__ s, ushort4* __restrict__ d, int n4) {
  int i = blockIdx.x * blockDim.x + threadIdx.x;
  const int st = gridDim.x * blockDim.x;
  for (; i < n4; i += st) {
    const float4 f = s[i];
    ushort4 v;
    v.x = bfbits(f.x); v.y = bfbits(f.y); v.z = bfbits(f.z); v.w = bfbits(f.w);
    d[i] = v;
  }
}

__global__ void k_bias(const float* __restrict__ a, const float* __restrict__ b,
                       float* __restrict__ o, int n) {
  const int i = blockIdx.x * blockDim.x + threadIdx.x;
  if (i < n) o[i] = a[i] + b[i];
}

// X[m][e] = bf16(embed[captions[b][t]][e]), m = t*64+b (t<63); pad rows -> 0
__global__ void k_gather(const float* __restrict__ embed, const int* __restrict__ caps,
                         unsigned short* __restrict__ X) {
  const int i = blockIdx.x * 256 + threadIdx.x;   // 2048 blocks * 256 = MPAD*E_/4 exact
  const int m = i >> 7, e4 = i & 127;             // 128 float4 per row
  ushort4 v;
  if (m < MROWS) {
    const int t = m >> 6, b = m & 63;
    const int idx = caps[b * T_ + t];
    const float4 f = ((const float4*)embed)[(long)idx * (E_ / 4) + e4];
    v.x = bfbits(f.x); v.y = bfbits(f.y); v.z = bfbits(f.z); v.w = bfbits(f.w);
  } else {
    v = make_ushort4(0, 0, 0, 0);
  }
  ((ushort4*)X)[i] = v;
}

// h0/h1 initial slots (bf16) + private fp32 copies of c0/c1 + zero barrier flags
__global__ void k_init(const float* __restrict__ hidden, const float* __restrict__ cell,
                       unsigned short* __restrict__ H0, unsigned short* __restrict__ H1,
                       float* __restrict__ c0, float* __restrict__ c1,
                       unsigned int* __restrict__ flags) {
  const int i = blockIdx.x * 256 + threadIdx.x;   // 256 blocks -> 65536 = B_*H_ exact
  H0[i] = bfbits(hidden[i]);
  H1[i] = bfbits(hidden[B_ * H_ + i]);
  c0[i] = cell[i];
  c1[i] = cell[B_ * H_ + i];
  if (i < 128) flags[i] = 0u;
}

__global__ void k_zeropad(unsigned short* __restrict__ a, unsigned short* __restrict__ b) {
  const int i = blockIdx.x * 256 + threadIdx.x;   // 65536
  a[i] = 0;
  b[i] = 0;
}

__global__ void k_zero_t0(float4* __restrict__ out4) {
  const int i = blockIdx.x * 256 + threadIdx.x;   // 2000 blocks -> 512000 = B_*V_/4 exact
  const int b = i / (V_ / 4), v = i - b * (V_ / 4);
  out4[(long)b * (T_ * V_ / 4) + v] = make_float4(0.f, 0.f, 0.f, 0.f);
}

// ---------------- big GEMM: C(MPADxN) = A(MPADxK) @ Bm(NxK)^T + bias ----------------
// m97 structure: 128x128 tile, BK=32, global_load_lds(16B), 2 barriers/K-step.
// TO_OUT=false: write bf16 C (row-major, stride N). TO_OUT=true: fp32 scatter to logits.
template <int KDIM, bool TO_OUT>
__global__ __launch_bounds__(256) void k_gemm(
    const unsigned short* __restrict__ A, const unsigned short* __restrict__ Bm,
    const float* __restrict__ bias, unsigned short* __restrict__ Cb,
    float* __restrict__ Cout, int N) {
  __shared__ unsigned short As[128 * 32];
  __shared__ unsigned short Bs[128 * 32];
  const int tid = threadIdx.x;
  const int w = tid >> 6, l = tid & 63;
  const int wm = (w >> 1) * 64, wn = (w & 1) * 64;
  const int lr = l & 15, lk = (l >> 4) * 8;
  const long am0 = (long)blockIdx.y * 128;
  const long bn0 = (long)blockIdx.x * 128;

  // staging: A/B tiles are 512 x 16B units each; 2 units/thread/tile
  const int u0 = tid, u1 = tid + 256;
  const char* gA0 = (const char*)(A + (am0 + (u0 >> 2)) * KDIM) + (u0 & 3) * 16;
  const char* gA1 = (const char*)(A + (am0 + (u1 >> 2)) * KDIM) + (u1 & 3) * 16;
  const char* gB0 = (const char*)(Bm + (bn0 + (u0 >> 2)) * KDIM) + (u0 & 3) * 16;
  const char* gB1 = (const char*)(Bm + (bn0 + (u1 >> 2)) * KDIM) + (u1 & 3) * 16;
  char* lA0 = (char*)As + u0 * 16; char* lA1 = (char*)As + u1 * 16;
  char* lB0 = (char*)Bs + u0 * 16; char* lB1 = (char*)Bs + u1 * 16;

  f32x4 acc[4][4];
  const f32x4 z = {0.f, 0.f, 0.f, 0.f};
  #pragma unroll
  for (int mi = 0; mi < 4; ++mi)
    #pragma unroll
    for (int ni = 0; ni < 4; ++ni) acc[mi][ni] = z;

  for (int k0 = 0; k0 < KDIM; k0 += 32) {
    __syncthreads();                       // previous iter's ds_reads done
    gload16(gA0 + (long)k0 * 2, lA0);
    gload16(gA1 + (long)k0 * 2, lA1);
    gload16(gB0 + (long)k0 * 2, lB0);
    gload16(gB1 + (long)k0 * 2, lB1);
    __syncthreads();                       // vmcnt(0) drain -> LDS ready
    bf16x8 af[4], bfr[4];
    #pragma unroll
    for (int mi = 0; mi < 4; ++mi)
      af[mi] = *(const bf16x8*)(As + (wm + mi * 16 + lr) * 32 + lk);
    #pragma unroll
    for (int ni = 0; ni < 4; ++ni)
      bfr[ni] = *(const bf16x8*)(Bs + (wn + ni * 16 + lr) * 32 + lk);
    #pragma unroll
    for (int mi = 0; mi < 4; ++mi)
      #pragma unroll
      for (int ni = 0; ni < 4; ++ni)
        acc[mi][ni] = __builtin_amdgcn_mfma_f32_16x16x32_bf16(af[mi], bfr[ni], acc[mi][ni], 0, 0, 0);
  }

  // epilogue: C/D layout col=lane&15, row=(lane>>4)*4+r
  #pragma unroll
  for (int ni = 0; ni < 4; ++ni) {
    const int n = (int)bn0 + wn + ni * 16 + lr;
    const float bv = bias[n];
    #pragma unroll
    for (int mi = 0; mi < 4; ++mi) {
      #pragma unroll
      for (int r = 0; r < 4; ++r) {
        const int m = (int)am0 + wm + mi * 16 + (l >> 4) * 4 + r;
        const float v = acc[mi][ni][r] + bv;
        if constexpr (TO_OUT) {
          if (m < MROWS) {
            const int t = m >> 6, b = m & 63;
            Cout[(long)(b * T_ + t + 1) * V_ + n] = v;   // logits of step t -> out[:,t+1,:]
          }
        } else {
          Cb[(long)m * N + n] = bfbits(v);
        }
      }
    }
  }
}

// ---------------- persistent recurrence: 63 LSTM steps in one kernel ----------------
// 64 blocks (1/CU, co-resident), block nb owns j-slice jb=nb*16 across all 4 gates.
// W_hh slice staged once in LDS (XOR-swizzled). Wave w owns batch rows w*16..+15,
// computes all 4 gates; c-state in registers.
// Cross-XCD protocol — NO fences (no wbl2/inv full-cache ops):
//   - h stores:  global_store_short sc0 sc1 (write-through to device coherence point)
//   - arrive:    flags[block] = t+1 via sc0 sc1 dword store (contention-free)
//   - wait:      wave-0 lanes poll flags[lane] via one coalesced sc0 sc1 load/spin
//   - h loads:   PLAIN (L2-cached): slot t+1 lines can only demand-fill into a
//                reader L2 after its barrier exit, i.e. after data reached L3.
__global__ __launch_bounds__(256) void k_recur(
    const unsigned short* __restrict__ W,    // [4096][1024] bf16
    const unsigned short* __restrict__ In,   // [63][64][4096] bf16 (x-proj + bias)
    unsigned short* __restrict__ Hbuf,       // [64+][64][1024] bf16, slot 0 = init
    const float* __restrict__ cinit,         // [64][1024] fp32
    unsigned int* __restrict__ flags) {      // [64] zeroed per-block step flags
  __shared__ unsigned short Wl[64 * 1024];   // 128 KB
  const int tid = threadIdx.x;
  const int w = tid >> 6, l = tid & 63;
  const int jb = blockIdx.x << 4;
  const int lcol = l & 15, khi = l >> 4;
  const int bw = w * 16;

  // stage W slice: LDS row rr = g*16+jj <- W row g*1024+jb+jj; swizzle 16B unit ^ (jj&7)
  for (int u = tid; u < 64 * 128; u += 256) {
    const int rr = u >> 7, cu = u & 127;
    const int g = rr >> 4, jj = rr & 15;
    const bf16x8 v = *(const bf16x8*)(W + ((size_t)(g * 1024 + jb + jj)) * H_ + cu * 8);
    ((bf16x8*)Wl)[rr * 128 + (cu ^ (jj & 7))] = v;
  }
  // initial cell state in registers
  f32x4 cr;
  #pragma unroll
  for (int r = 0; r < 4; ++r)
    cr[r] = cinit[(size_t)(bw + khi * 4 + r) * H_ + jb + lcol];

  // prefetch In[0] into registers (static indexing -> stays in VGPRs)
  unsigned short pin[16];
  #pragma unroll
  for (int r = 0; r < 4; ++r) {
    const unsigned short* ir = In + (size_t)(bw + khi * 4 + r) * G4_ + jb + lcol;
    pin[r * 4 + 0] = ir[0];
    pin[r * 4 + 1] = ir[H_];
    pin[r * 4 + 2] = ir[2 * H_];
    pin[r * 4 + 3] = ir[3 * H_];
  }
  __syncthreads();

  for (int t = 0; t < TS_; ++t) {
    // accumulators init = prefetched input projection (+bias), fp32
    f32x4 a0, a1, a2, a3;
    #pragma unroll
    for (int r = 0; r < 4; ++r) {
      a0[r] = bf2f(pin[r * 4 + 0]);
      a1[r] = bf2f(pin[r * 4 + 1]);
      a2[r] = bf2f(pin[r * 4 + 2]);
      a3[r] = bf2f(pin[r * 4 + 3]);
    }
    // gates += hin @ Wslice^T   (A from global plain loads, B from LDS)
    const unsigned short* hrow = Hbuf + (size_t)t * (B_ * H_) + (size_t)(bw + lcol) * H_ + khi * 8;
    #pragma unroll 8
    for (int kk = 0; kk < 32; ++kk) {
      const bf16x8 av = *(const bf16x8*)(hrow + kk * 32);
      const bf16x8 b0 = ((const bf16x8*)Wl)[(0 * 16 + lcol) * 128 + ((kk * 4 + khi) ^ (lcol & 7))];
      const bf16x8 b1 = ((const bf16x8*)Wl)[(1 * 16 + lcol) * 128 + ((kk * 4 + khi) ^ (lcol & 7))];
      const bf16x8 b2 = ((const bf16x8*)Wl)[(2 * 16 + lcol) * 128 + ((kk * 4 + khi) ^ (lcol & 7))];
      const bf16x8 b3 = ((const bf16x8*)Wl)[(3 * 16 + lcol) * 128 + ((kk * 4 + khi) ^ (lcol & 7))];
      a0 = __builtin_amdgcn_mfma_f32_16x16x32_bf16(av, b0, a0, 0, 0, 0);
      a1 = __builtin_amdgcn_mfma_f32_16x16x32_bf16(av, b1, a1, 0, 0, 0);
      a2 = __builtin_amdgcn_mfma_f32_16x16x32_bf16(av, b2, a2, 0, 0, 0);
      a3 = __builtin_amdgcn_mfma_f32_16x16x32_bf16(av, b3, a3, 0, 0, 0);
    }
    // LSTM cell update; h -> Hbuf slot t+1 via device-coherent stores
    unsigned short* hop = Hbuf + (size_t)(t + 1) * (B_ * H_);
    #pragma unroll
    for (int r = 0; r < 4; ++r) {
      const float gi = 1.f / (1.f + __expf(-a0[r]));
      const float gf = 1.f / (1.f + __expf(-a1[r]));
      const float gg = tanhf(a2[r]);
      const float go = 1.f / (1.f + __expf(-a3[r]));
      cr[r] = gf * cr[r] + gi * gg;
      store_short_dc(hop + (size_t)(bw + khi * 4 + r) * H_ + jb + lcol,
                     bfbits(go * tanhf(cr[r])));
    }
    // prefetch In[t+1] before the barrier (read-only; regs unaffected by sync)
    if (t + 1 < TS_) {
      const unsigned short* inb = In + (size_t)(t + 1) * (B_ * G4_);
      #pragma unroll
      for (int r = 0; r < 4; ++r) {
        const unsigned short* ir = inb + (size_t)(bw + khi * 4 + r) * G4_ + jb + lcol;
        pin[r * 4 + 0] = ir[0];
        pin[r * 4 + 1] = ir[H_];
        pin[r * 4 + 2] = ir[2 * H_];
        pin[r * 4 + 3] = ir[3 * H_];
      }
    }
    // inter-block step barrier (skip after last step)
    if (t < TS_ - 1) {
      __syncthreads();   // per-wave vmcnt(0): all sc0sc1 h-stores are at coherence point
      if (tid < 64) {
        if (tid == 0) store_dword_dc(&flags[blockIdx.x], (unsigned int)(t + 1));
        while (load_dword_dc(&flags[tid]) < (unsigned int)(t + 1)) {
        }
      }
      __syncthreads();
    }
  }
}

// ---------------- launch ----------------

extern "C" void kernel_launch(void* const* d_in, const int* in_sizes, int n_in,
                              void* d_out, int out_size, void* d_ws, size_t ws_size,
                              hipStream_t stream) {
  (void)in_sizes; (void)n_in; (void)out_size; (void)ws_size;
  const float* hidden = (const float*)d_in[0];
  const float* cell   = (const float*)d_in[1];
  const int*   caps   = (const int*)d_in[2];
  const float* embed  = (const float*)d_in[3];
  const float* Wih0   = (const float*)d_in[4];
  const float* Whh0   = (const float*)d_in[5];
  const float* bih0   = (const float*)d_in[6];
  const float* bhh0   = (const float*)d_in[7];
  const float* Wih1   = (const float*)d_in[8];
  const float* Whh1   = (const float*)d_in[9];
  const float* bih1   = (const float*)d_in[10];
  const float* bhh1   = (const float*)d_in[11];
  const float* Wp     = (const float*)d_in[12];
  const float* bp     = (const float*)d_in[13];
  float* out = (float*)d_out;

  // workspace layout (~240 MB)
  char* p = (char*)d_ws;
  auto alloc = [&](size_t bytes) { char* r = p; p += (bytes + 255) & ~(size_t)255; return r; };
  unsigned short* Xbf   = (unsigned short*)alloc((size_t)MPAD * E_ * 2);
  unsigned short* Wih0b = (unsigned short*)alloc((size_t)G4_ * E_ * 2);
  unsigned short* Whh0b = (unsigned short*)alloc((size_t)G4_ * H_ * 2);
  unsigned short* Wih1b = (unsigned short*)alloc((size_t)G4_ * H_ * 2);
  unsigned short* Whh1b = (unsigned short*)alloc((size_t)G4_ * H_ * 2);
  unsigned short* Wpb   = (unsigned short*)alloc((size_t)V_ * H_ * 2);
  unsigned short* Xp    = (unsigned short*)alloc((size_t)MPAD * G4_ * 2);
  unsigned short* Yp    = (unsigned short*)alloc((size_t)MPAD * G4_ * 2);
  unsigned short* H0    = (unsigned short*)alloc((size_t)(MPAD + B_) * H_ * 2);  // slots 0..64 + pad
  unsigned short* H1    = (unsigned short*)alloc((size_t)(MPAD + B_) * H_ * 2);
  float* c0  = (float*)alloc((size_t)B_ * H_ * 4);
  float* c1  = (float*)alloc((size_t)B_ * H_ * 4);
  float* b0s = (float*)alloc((size_t)G4_ * 4);
  float* b1s = (float*)alloc((size_t)G4_ * 4);
  unsigned int* cbar = (unsigned int*)alloc(128 * 4);

  // weight casts fp32 -> bf16
  k_cast4<<<2048, 256, 0, stream>>>((const float4*)Wih0, (ushort4*)Wih0b, G4_ * E_ / 4);
  k_cast4<<<2048, 256, 0, stream>>>((const float4*)Whh0, (ushort4*)Whh0b, G4_ * H_ / 4);
  k_cast4<<<2048, 256, 0, stream>>>((const float4*)Wih1, (ushort4*)Wih1b, G4_ * H_ / 4);
  k_cast4<<<2048, 256, 0, stream>>>((const float4*)Whh1, (ushort4*)Whh1b, G4_ * H_ / 4);
  k_cast4<<<4096, 256, 0, stream>>>((const float4*)Wp,   (ushort4*)Wpb,   V_ * H_ / 4);
  k_bias<<<16, 256, 0, stream>>>(bih0, bhh0, b0s, G4_);
  k_bias<<<16, 256, 0, stream>>>(bih1, bhh1, b1s, G4_);
  k_gather<<<2048, 256, 0, stream>>>(embed, caps, Xbf);
  k_init<<<256, 256, 0, stream>>>(hidden, cell, H0, H1, c0, c1, cbar);
  k_zeropad<<<256, 256, 0, stream>>>(H0 + (size_t)MPAD * H_, H1 + (size_t)MPAD * H_);
  k_zero_t0<<<2000, 256, 0, stream>>>((float4*)out);

  // GEMM1: Xp = X @ W_ih0^T + b0   (M=4096, N=4096, K=512)
  k_gemm<512, false><<<dim3(32, 32), 256, 0, stream>>>(Xbf, Wih0b, b0s, Xp, nullptr, G4_);

  // layer-0 recurrence: all 63 steps in one persistent kernel
  k_recur<<<64, 256, 0, stream>>>(Whh0b, Xp, H0, c0, cbar);

  // GEMM2: Yp = H0[1..63] @ W_ih1^T + b1   (M=4096, N=4096, K=1024)
  k_gemm<1024, false><<<dim3(32, 32), 256, 0, stream>>>(H0 + (size_t)B_ * H_, Wih1b, b1s, Yp, nullptr, G4_);

  // layer-1 recurrence
  k_recur<<<64, 256, 0, stream>>>(Whh1b, Yp, H1, c1, cbar + 64);

  // GEMM3: logits = H1[1..63] @ Wp^T + bp -> out[:,1:,:]   (M=4096(4032), N=32000, K=1024)
  k_gemm<1024, true><<<dim3(250, 32), 256, 0, stream>>>(H1 + (size_t)B_ * H_, Wpb, bp, nullptr, out, V_);
}

// Round 5
// 1275.523 us; speedup vs baseline: 2.7977x; 1.4312x over previous
//
#include <hip/hip_runtime.h>

#define B_    64
#define T_    64
#define V_    32000
#define E_    512
#define H_    1024
#define G4_   4096      // 4*H
#define TS_   63        // time steps actually computed
#define MROWS 4032      // TS_*B_
#define MPAD  4096
#define BH    (B_ * H_)

typedef __attribute__((ext_vector_type(8))) short bf16x8;   // 8 bf16 = 4 VGPR
typedef __attribute__((ext_vector_type(4))) float f32x4;
typedef __attribute__((ext_vector_type(4))) unsigned int uint32x4;

__device__ __forceinline__ unsigned short bfbits(float f) {  // fp32 -> bf16 (RNE)
  union { float f; unsigned int u; } cv; cv.f = f;
  unsigned int u = cv.u;
  u += 0x7fffu + ((u >> 16) & 1u);
  return (unsigned short)(u >> 16);
}
__device__ __forceinline__ float bf2f(unsigned short h) {
  union { unsigned int u; float f; } cv; cv.u = ((unsigned int)h) << 16;
  return cv.f;
}
__device__ __forceinline__ float fsig(float x) { return 1.f / (1.f + __expf(-x)); }
__device__ __forceinline__ float ftanh(float x) {
  x = fminf(fmaxf(x, -10.f), 10.f);
  const float e = __expf(2.f * x);
  return (e - 1.f) / (e + 1.f);
}

// ---- device-coherent (sc0 sc1) accesses: bypass the non-coherent per-XCD L2.
__device__ __forceinline__ void store_dword_dc(void* p, unsigned int v) {
  asm volatile("global_store_dword %0, %1, off sc0 sc1" :: "v"(p), "v"(v) : "memory");
}
__device__ __forceinline__ void store_b128_dc(void* p, uint32x4 v) {
  asm volatile("global_store_dwordx4 %0, %1, off sc0 sc1" :: "v"(p), "v"(v) : "memory");
}
__device__ __forceinline__ unsigned int load_dword_dc(const void* p) {
  unsigned int v;
  asm volatile("global_load_dword %0, %1, off sc0 sc1\n\ts_waitcnt vmcnt(0)"
               : "=v"(v) : "v"(p) : "memory");
  return v;
}

// async global->LDS, 16B per lane (wave-uniform LDS base + lane*16)
__device__ __forceinline__ void gload16(const void* g, void* l) {
  __builtin_amdgcn_global_load_lds(
      (const __attribute__((address_space(1))) unsigned int*)g,
      (__attribute__((address_space(3))) unsigned int*)l, 16, 0, 0);
}

// ---------------- elementwise / init kernels ----------------

__global__ void k_cast4(const float4* __restrict__ s, ushort4* __restrict__ d, int n4) {
  int i = blockIdx.x * blockDim.x + threadIdx.x;
  const int st = gridDim.x * blockDim.x;
  for (; i < n4; i += st) {
    const float4 f = s[i];
    ushort4 v;
    v.x = bfbits(f.x); v.y = bfbits(f.y); v.z = bfbits(f.z); v.w = bfbits(f.w);
    d[i] = v;
  }
}

__global__ void k_bias(const float* __restrict__ a, const float* __restrict__ b,
                       float* __restrict__ o, int n) {
  const int i = blockIdx.x * blockDim.x + threadIdx.x;
  if (i < n) o[i] = a[i] + b[i];
}

// X[m][e] = bf16(embed[captions[b][t]][e]), m = t*64+b (t<63); pad rows -> 0
__global__ void k_gather(const float* __restrict__ embed, const int* __restrict__ caps,
                         unsigned short* __restrict__ X) {
  const int i = blockIdx.x * 256 + threadIdx.x;   // 2048 blocks * 256 = MPAD*E_/4 exact
  const int m = i >> 7, e4 = i & 127;             // 128 float4 per row
  ushort4 v;
  if (m < MROWS) {
    const int t = m >> 6, b = m & 63;
    const int idx = caps[b * T_ + t];
    const float4 f = ((const float4*)embed)[(long)idx * (E_ / 4) + e4];
    v.x = bfbits(f.x); v.y = bfbits(f.y); v.z = bfbits(f.z); v.w = bfbits(f.w);
  } else {
    v = make_ushort4(0, 0, 0, 0);
  }
  ((ushort4*)X)[i] = v;
}

// h0/h1 initial slots (bf16) + private fp32 copies of c0/c1 + zero barrier flags
__global__ void k_init(const float* __restrict__ hidden, const float* __restrict__ cell,
                       unsigned short* __restrict__ H0, unsigned short* __restrict__ H1,
                       float* __restrict__ c0, float* __restrict__ c1,
                       unsigned int* __restrict__ flags) {
  const int i = blockIdx.x * 256 + threadIdx.x;   // 256 blocks -> 65536 = B_*H_ exact
  H0[i] = bfbits(hidden[i]);
  H1[i] = bfbits(hidden[B_ * H_ + i]);
  c0[i] = cell[i];
  c1[i] = cell[B_ * H_ + i];
  if (i < 256) flags[i] = 0u;
}

__global__ void k_zeropad(unsigned short* __restrict__ a, unsigned short* __restrict__ b) {
  const int i = blockIdx.x * 256 + threadIdx.x;   // 65536
  a[i] = 0;
  b[i] = 0;
}

__global__ void k_zero_t0(float4* __restrict__ out4) {
  const int i = blockIdx.x * 256 + threadIdx.x;   // 2000 blocks -> 512000 = B_*V_/4 exact
  const int b = i / (V_ / 4), v = i - b * (V_ / 4);
  out4[(long)b * (T_ * V_ / 4) + v] = make_float4(0.f, 0.f, 0.f, 0.f);
}

// ---------------- big GEMM: C(MPADxN) = A(MPADxK) @ Bm(NxK)^T + bias ----------------
template <int KDIM, bool TO_OUT>
__global__ __launch_bounds__(256) void k_gemm(
    const unsigned short* __restrict__ A, const unsigned short* __restrict__ Bm,
    const float* __restrict__ bias, unsigned short* __restrict__ Cb,
    float* __restrict__ Cout, int N) {
  __shared__ unsigned short As[128 * 32];
  __shared__ unsigned short Bs[128 * 32];
  const int tid = threadIdx.x;
  const int w = tid >> 6, l = tid & 63;
  const int wm = (w >> 1) * 64, wn = (w & 1) * 64;
  const int lr = l & 15, lk = (l >> 4) * 8;
  const long am0 = (long)blockIdx.y * 128;
  const long bn0 = (long)blockIdx.x * 128;

  const int u0 = tid, u1 = tid + 256;
  const char* gA0 = (const char*)(A + (am0 + (u0 >> 2)) * KDIM) + (u0 & 3) * 16;
  const char* gA1 = (const char*)(A + (am0 + (u1 >> 2)) * KDIM) + (u1 & 3) * 16;
  const char* gB0 = (const char*)(Bm + (bn0 + (u0 >> 2)) * KDIM) + (u0 & 3) * 16;
  const char* gB1 = (const char*)(Bm + (bn0 + (u1 >> 2)) * KDIM) + (u1 & 3) * 16;
  char* lA0 = (char*)As + u0 * 16; char* lA1 = (char*)As + u1 * 16;
  char* lB0 = (char*)Bs + u0 * 16; char* lB1 = (char*)Bs + u1 * 16;

  f32x4 acc[4][4];
  const f32x4 z = {0.f, 0.f, 0.f, 0.f};
  #pragma unroll
  for (int mi = 0; mi < 4; ++mi)
    #pragma unroll
    for (int ni = 0; ni < 4; ++ni) acc[mi][ni] = z;

  for (int k0 = 0; k0 < KDIM; k0 += 32) {
    __syncthreads();
    gload16(gA0 + (long)k0 * 2, lA0);
    gload16(gA1 + (long)k0 * 2, lA1);
    gload16(gB0 + (long)k0 * 2, lB0);
    gload16(gB1 + (long)k0 * 2, lB1);
    __syncthreads();
    bf16x8 af[4], bfr[4];
    #pragma unroll
    for (int mi = 0; mi < 4; ++mi)
      af[mi] = *(const bf16x8*)(As + (wm + mi * 16 + lr) * 32 + lk);
    #pragma unroll
    for (int ni = 0; ni < 4; ++ni)
      bfr[ni] = *(const bf16x8*)(Bs + (wn + ni * 16 + lr) * 32 + lk);
    #pragma unroll
    for (int mi = 0; mi < 4; ++mi)
      #pragma unroll
      for (int ni = 0; ni < 4; ++ni)
        acc[mi][ni] = __builtin_amdgcn_mfma_f32_16x16x32_bf16(af[mi], bfr[ni], acc[mi][ni], 0, 0, 0);
  }

  #pragma unroll
  for (int ni = 0; ni < 4; ++ni) {
    const int n = (int)bn0 + wn + ni * 16 + lr;
    const float bv = bias[n];
    #pragma unroll
    for (int mi = 0; mi < 4; ++mi) {
      #pragma unroll
      for (int r = 0; r < 4; ++r) {
        const int m = (int)am0 + wm + mi * 16 + (l >> 4) * 4 + r;
        const float v = acc[mi][ni][r] + bv;
        if constexpr (TO_OUT) {
          if (m < MROWS) {
            const int t = m >> 6, b = m & 63;
            Cout[(long)(b * T_ + t + 1) * V_ + n] = v;
          }
        } else {
          Cb[(long)m * N + n] = bfbits(v);
        }
      }
    }
  }
}

// ---------------- fused 2-layer persistent recurrence ----------------
// 192 co-resident blocks (1/CU), two concurrent teams:
//   team-0 = blocks 0..63:   layer-0, 16 j-cols each; stage s computes h0[s+1].
//     Waits only on its OWN team's flags -> never stalled by team-1.
//   team-1 = blocks 64..191: layer-1, 8 j-cols each; stage s computes
//     h1[s] = cell(h1[s-1]@Whh1^T + h0[s]@Wih1^T + b1) as one K=2048 loop
//     (Whh1 + Wih1 slices both in LDS). Runs one stage behind team-0.
// => 63 serial barrier stages total (vs 126), GEMM2 eliminated.
// Cross-XCD protocol (validated R4): sc0sc1 write-through h stores + per-block
// flag array polled with sc0sc1 loads; data reads stay plain/L2-cached (slot
// lines can only demand-fill after the flag gate). h stores coalesced via LDS
// transpose (16B team-0 / 4B team-1), replacing 2B scatter stores.
__global__ __launch_bounds__(256) void k_fused(
    const unsigned short* __restrict__ Whh0b,  // [4096][1024] bf16
    const unsigned short* __restrict__ Whh1b,  // [4096][1024] bf16
    const unsigned short* __restrict__ Wih1b,  // [4096][1024] bf16
    const unsigned short* __restrict__ Xp,     // [63][64][4096] bf16 (x-proj + b0)
    unsigned short* __restrict__ H0b,          // [65][64][1024] bf16, slot 0 init
    unsigned short* __restrict__ H1b,          // [65][64][1024] bf16, slot 0 init
    const float* __restrict__ c0i, const float* __restrict__ c1i,
    const float* __restrict__ b1s,             // [4096] f32
    unsigned int* __restrict__ f0,             // [64]  zeroed
    unsigned int* __restrict__ f1) {           // [128] zeroed
  __shared__ unsigned short Wl[64 * 1024];     // 128 KB
  __shared__ __align__(16) float gs1[4][64][8];  // 8 KB (team-1); aliased by team-0
  unsigned short (*hexch)[16] = (unsigned short (*)[16])gs1;

  const int tid = threadIdx.x;
  const int w = tid >> 6, l = tid & 63;
  const int lcol = l & 15, khi = l >> 4;
  const int bw = w * 16;
  const f32x4 z = {0.f, 0.f, 0.f, 0.f};

  if (blockIdx.x < 64) {
    // ================= TEAM 0 : layer 0 =================
    const int blk = blockIdx.x;
    const int jb = blk << 4;
    // stage Whh0 slice: packed row rr = g*16+jj <- W row g*1024+jb+jj
    for (int u = tid; u < 64 * 128; u += 256) {
      const int rr = u >> 7, cu = u & 127;
      const int g = rr >> 4, jj = rr & 15;
      ((bf16x8*)Wl)[rr * 128 + (cu ^ (rr & 7))] =
          *(const bf16x8*)(Whh0b + (size_t)(g * 1024 + jb + jj) * H_ + cu * 8);
    }
    f32x4 cr;
    #pragma unroll
    for (int r = 0; r < 4; ++r)
      cr[r] = c0i[(size_t)(bw + khi * 4 + r) * H_ + jb + lcol];
    // prefetch In[0]
    unsigned short pin[16];
    #pragma unroll
    for (int r = 0; r < 4; ++r) {
      const unsigned short* ir = Xp + (size_t)(bw + khi * 4 + r) * G4_ + jb + lcol;
      pin[r * 4 + 0] = ir[0];
      pin[r * 4 + 1] = ir[H_];
      pin[r * 4 + 2] = ir[2 * H_];
      pin[r * 4 + 3] = ir[3 * H_];
    }
    __syncthreads();

    for (int s = 0; s < TS_; ++s) {
      if (s > 0) {
        if (tid < 64)
          while (load_dword_dc(&f0[tid]) < (unsigned)s) {}
        __syncthreads();
      }
      f32x4 a0, a1, a2, a3;
      #pragma unroll
      for (int r = 0; r < 4; ++r) {
        a0[r] = bf2f(pin[r * 4 + 0]);
        a1[r] = bf2f(pin[r * 4 + 1]);
        a2[r] = bf2f(pin[r * 4 + 2]);
        a3[r] = bf2f(pin[r * 4 + 3]);
      }
      const unsigned short* hrow = H0b + (size_t)s * BH + (size_t)(bw + lcol) * H_ + khi * 8;
      #pragma unroll 8
      for (int kk = 0; kk < 32; ++kk) {
        const bf16x8 av = *(const bf16x8*)(hrow + kk * 32);
        const int un = (kk * 4 + khi) ^ (lcol & 7);
        const bf16x8 b0 = ((const bf16x8*)Wl)[(0 * 16 + lcol) * 128 + un];
        const bf16x8 b1 = ((const bf16x8*)Wl)[(1 * 16 + lcol) * 128 + un];
        const bf16x8 b2 = ((const bf16x8*)Wl)[(2 * 16 + lcol) * 128 + un];
        const bf16x8 b3 = ((const bf16x8*)Wl)[(3 * 16 + lcol) * 128 + un];
        a0 = __builtin_amdgcn_mfma_f32_16x16x32_bf16(av, b0, a0, 0, 0, 0);
        a1 = __builtin_amdgcn_mfma_f32_16x16x32_bf16(av, b1, a1, 0, 0, 0);
        a2 = __builtin_amdgcn_mfma_f32_16x16x32_bf16(av, b2, a2, 0, 0, 0);
        a3 = __builtin_amdgcn_mfma_f32_16x16x32_bf16(av, b3, a3, 0, 0, 0);
      }
      // cell update -> hexch (LDS transpose for coalesced stores)
      #pragma unroll
      for (int r = 0; r < 4; ++r) {
        const float gi = fsig(a0[r]);
        const float gf = fsig(a1[r]);
        const float gg = ftanh(a2[r]);
        const float go = fsig(a3[r]);
        cr[r] = gf * cr[r] + gi * gg;
        hexch[bw + khi * 4 + r][lcol] = bfbits(go * ftanh(cr[r]));
      }
      // prefetch In[s+1] (latency hidden behind barrier/poll)
      if (s + 1 < TS_) {
        const unsigned short* inb = Xp + (size_t)(s + 1) * (B_ * G4_);
        #pragma unroll
        for (int r = 0; r < 4; ++r) {
          const unsigned short* ir = inb + (size_t)(bw + khi * 4 + r) * G4_ + jb + lcol;
          pin[r * 4 + 0] = ir[0];
          pin[r * 4 + 1] = ir[H_];
          pin[r * 4 + 2] = ir[2 * H_];
          pin[r * 4 + 3] = ir[3 * H_];
        }
      }
      __syncthreads();                       // hexch complete
      if (tid < 128) {                       // coalesced 16B device-coherent stores
        const int b = tid >> 1, hf = tid & 1;
        const uint32x4 v = *(const uint32x4*)&hexch[b][hf * 8];
        store_b128_dc(H0b + (size_t)(s + 1) * BH + (size_t)b * H_ + jb + hf * 8, v);
      }
      __syncthreads();                       // drain stores (per-wave vmcnt)
      if (tid == 0) store_dword_dc(&f0[blk], (unsigned)(s + 1));
    }
  } else {
    // ================= TEAM 1 : layer 1 =================
    const int blk1 = blockIdx.x - 64;
    const int jb1 = blk1 << 3;
    // stage Wcat: packed rows 0..31 = Whh1 tiles, 32..63 = Wih1 tiles
    // packed row pr: prl=pr&31, tt=prl>>4, lr=prl&15, g=tt*2+(lr>>3), jj=lr&7
    for (int u = tid; u < 64 * 128; u += 256) {
      const int pr = u >> 7, cu = u & 127;
      const int prl = pr & 31, tt = prl >> 4, lr_ = prl & 15;
      const int g = tt * 2 + (lr_ >> 3), jj = lr_ & 7;
      const unsigned short* src =
          ((pr >> 5) ? Wih1b : Whh1b) + (size_t)(g * 1024 + jb1 + jj) * H_ + cu * 8;
      ((bf16x8*)Wl)[pr * 128 + (cu ^ (pr & 7))] = *(const bf16x8*)src;
    }
    // per-thread cell items: item0=(bb,j0), item1=(bb,j0+1)
    const int bb = tid >> 2;
    const int j0 = (tid * 2) & 7;
    float cA = c1i[(size_t)bb * H_ + jb1 + j0];
    float cB = c1i[(size_t)bb * H_ + jb1 + j0 + 1];
    float biA[4], biB[4];
    #pragma unroll
    for (int g = 0; g < 4; ++g) {
      biA[g] = b1s[g * 1024 + jb1 + j0];
      biB[g] = b1s[g * 1024 + jb1 + j0 + 1];
    }
    __syncthreads();

    for (int s = 1; s <= TS_; ++s) {
      {  // poll: h0[s] ready (f0 >= s) and h1[s-1] ready (f1 >= s-1)
        const unsigned t0 = (unsigned)s, t1 = (unsigned)(s - 1);
        if (tid < 64) {
          while (load_dword_dc(&f0[tid]) < t0) {}
        } else if (tid < 192) {
          while (load_dword_dc(&f1[tid - 64]) < t1) {}
        }
        __syncthreads();
      }
      f32x4 ac0 = z, ac1 = z;
      const unsigned short* a1p = H1b + (size_t)(s - 1) * BH + (size_t)(bw + lcol) * H_ + khi * 8;
      const unsigned short* a0p = H0b + (size_t)s * BH + (size_t)(bw + lcol) * H_ + khi * 8;
      #pragma unroll 8
      for (int kk = 0; kk < 32; ++kk) {
        const bf16x8 av = *(const bf16x8*)(a1p + kk * 32);
        const int un = (kk * 4 + khi) ^ (lcol & 7);
        const bf16x8 b0 = ((const bf16x8*)Wl)[(0 + lcol) * 128 + un];
        const bf16x8 b1 = ((const bf16x8*)Wl)[(16 + lcol) * 128 + un];
        ac0 = __builtin_amdgcn_mfma_f32_16x16x32_bf16(av, b0, ac0, 0, 0, 0);
        ac1 = __builtin_amdgcn_mfma_f32_16x16x32_bf16(av, b1, ac1, 0, 0, 0);
      }
      #pragma unroll 8
      for (int kk = 0; kk < 32; ++kk) {
        const bf16x8 av = *(const bf16x8*)(a0p + kk * 32);
        const int un = (kk * 4 + khi) ^ (lcol & 7);
        const bf16x8 b0 = ((const bf16x8*)Wl)[(32 + lcol) * 128 + un];
        const bf16x8 b1 = ((const bf16x8*)Wl)[(48 + lcol) * 128 + un];
        ac0 = __builtin_amdgcn_mfma_f32_16x16x32_bf16(av, b0, ac0, 0, 0, 0);
        ac1 = __builtin_amdgcn_mfma_f32_16x16x32_bf16(av, b1, ac1, 0, 0, 0);
      }
      // acc -> gate-exchange LDS: tile0 -> gates 0/1, tile1 -> gates 2/3
      #pragma unroll
      for (int r = 0; r < 4; ++r) {
        const int b = bw + khi * 4 + r;
        gs1[lcol >> 3][b][lcol & 7] = ac0[r];
        gs1[2 + (lcol >> 3)][b][lcol & 7] = ac1[r];
      }
      __syncthreads();
      // cell update: 2 items/thread, then one 4B device-coherent store
      {
        const float giA = fsig(gs1[0][bb][j0] + biA[0]);
        const float gfA = fsig(gs1[1][bb][j0] + biA[1]);
        const float ggA = ftanh(gs1[2][bb][j0] + biA[2]);
        const float goA = fsig(gs1[3][bb][j0] + biA[3]);
        cA = gfA * cA + giA * ggA;
        const unsigned short hA = bfbits(goA * ftanh(cA));
        const float giB = fsig(gs1[0][bb][j0 + 1] + biB[0]);
        const float gfB = fsig(gs1[1][bb][j0 + 1] + biB[1]);
        const float ggB = ftanh(gs1[2][bb][j0 + 1] + biB[2]);
        const float goB = fsig(gs1[3][bb][j0 + 1] + biB[3]);
        cB = gfB * cB + giB * ggB;
        const unsigned short hB = bfbits(goB * ftanh(cB));
        const unsigned int hv = ((unsigned int)hB << 16) | hA;
        store_dword_dc(H1b + (size_t)s * BH + (size_t)bb * H_ + jb1 + j0, hv);
      }
      __syncthreads();                       // drain stores + gs1 WAR protection
      if (tid == 0) store_dword_dc(&f1[blk1], (unsigned)s);
    }
  }
}

// ---------------- launch ----------------

extern "C" void kernel_launch(void* const* d_in, const int* in_sizes, int n_in,
                              void* d_out, int out_size, void* d_ws, size_t ws_size,
                              hipStream_t stream) {
  (void)in_sizes; (void)n_in; (void)out_size; (void)ws_size;
  const float* hidden = (const float*)d_in[0];
  const float* cell   = (const float*)d_in[1];
  const int*   caps   = (const int*)d_in[2];
  const float* embed  = (const float*)d_in[3];
  const float* Wih0   = (const float*)d_in[4];
  const float* Whh0   = (const float*)d_in[5];
  const float* bih0   = (const float*)d_in[6];
  const float* bhh0   = (const float*)d_in[7];
  const float* Wih1   = (const float*)d_in[8];
  const float* Whh1   = (const float*)d_in[9];
  const float* bih1   = (const float*)d_in[10];
  const float* bhh1   = (const float*)d_in[11];
  const float* Wp     = (const float*)d_in[12];
  const float* bp     = (const float*)d_in[13];
  float* out = (float*)d_out;

  // workspace layout (~210 MB)
  char* p = (char*)d_ws;
  auto alloc = [&](size_t bytes) { char* r = p; p += (bytes + 255) & ~(size_t)255; return r; };
  unsigned short* Xbf   = (unsigned short*)alloc((size_t)MPAD * E_ * 2);
  unsigned short* Wih0b = (unsigned short*)alloc((size_t)G4_ * E_ * 2);
  unsigned short* Whh0b = (unsigned short*)alloc((size_t)G4_ * H_ * 2);
  unsigned short* Wih1b = (unsigned short*)alloc((size_t)G4_ * H_ * 2);
  unsigned short* Whh1b = (unsigned short*)alloc((size_t)G4_ * H_ * 2);
  unsigned short* Wpb   = (unsigned short*)alloc((size_t)V_ * H_ * 2);
  unsigned short* Xp    = (unsigned short*)alloc((size_t)MPAD * G4_ * 2);
  unsigned short* H0    = (unsigned short*)alloc((size_t)(MPAD + B_) * H_ * 2);  // slots 0..64
  unsigned short* H1    = (unsigned short*)alloc((size_t)(MPAD + B_) * H_ * 2);
  float* c0  = (float*)alloc((size_t)B_ * H_ * 4);
  float* c1  = (float*)alloc((size_t)B_ * H_ * 4);
  float* b0s = (float*)alloc((size_t)G4_ * 4);
  float* b1s = (float*)alloc((size_t)G4_ * 4);
  unsigned int* cbar = (unsigned int*)alloc(256 * 4);   // f0[64] | f1[128]

  k_cast4<<<2048, 256, 0, stream>>>((const float4*)Wih0, (ushort4*)Wih0b, G4_ * E_ / 4);
  k_cast4<<<2048, 256, 0, stream>>>((const float4*)Whh0, (ushort4*)Whh0b, G4_ * H_ / 4);
  k_cast4<<<2048, 256, 0, stream>>>((const float4*)Wih1, (ushort4*)Wih1b, G4_ * H_ / 4);
  k_cast4<<<2048, 256, 0, stream>>>((const float4*)Whh1, (ushort4*)Whh1b, G4_ * H_ / 4);
  k_cast4<<<4096, 256, 0, stream>>>((const float4*)Wp,   (ushort4*)Wpb,   V_ * H_ / 4);
  k_bias<<<16, 256, 0, stream>>>(bih0, bhh0, b0s, G4_);
  k_bias<<<16, 256, 0, stream>>>(bih1, bhh1, b1s, G4_);
  k_gather<<<2048, 256, 0, stream>>>(embed, caps, Xbf);
  k_init<<<256, 256, 0, stream>>>(hidden, cell, H0, H1, c0, c1, cbar);
  k_zeropad<<<256, 256, 0, stream>>>(H0 + (size_t)MPAD * H_, H1 + (size_t)MPAD * H_);
  k_zero_t0<<<2000, 256, 0, stream>>>((float4*)out);

  // GEMM1: Xp = X @ W_ih0^T + b0   (M=4096, N=4096, K=512)
  k_gemm<512, false><<<dim3(32, 32), 256, 0, stream>>>(Xbf, Wih0b, b0s, Xp, nullptr, G4_);

  // fused 2-layer recurrence (192 co-resident blocks, 63 pipelined stages)
  k_fused<<<192, 256, 0, stream>>>(Whh0b, Whh1b, Wih1b, Xp, H0, H1, c0, c1, b1s,
                                   cbar, cbar + 64);

  // GEMM3: logits = H1[1..63] @ Wp^T + bp -> out[:,1:,:]   (M=4096(4032), N=32000, K=1024)
  k_gemm<1024, true><<<dim3(250, 32), 256, 0, stream>>>(H1 + (size_t)B_ * H_, Wpb, bp, nullptr, out, V_);
}

// Round 6
// 1109.370 us; speedup vs baseline: 3.2167x; 1.1498x over previous
//
#include <hip/hip_runtime.h>

#define B_    64
#define T_    64
#define V_    32000
#define E_    512
#define H_    1024
#define G4_   4096      // 4*H
#define TS_   63        // time steps actually computed
#define MROWS 4032      // TS_*B_
#define MPAD  4096
#define BH    (B_ * H_)
#define FPAD  32        // flag padding: 32 dwords = 128 B (one L3 line per flag)

typedef __attribute__((ext_vector_type(8))) short bf16x8;   // 8 bf16 = 4 VGPR
typedef __attribute__((ext_vector_type(4))) float f32x4;
typedef __attribute__((ext_vector_type(4))) unsigned int uint32x4;

__device__ __forceinline__ unsigned short bfbits(float f) {  // fp32 -> bf16 (RNE)
  union { float f; unsigned int u; } cv; cv.f = f;
  unsigned int u = cv.u;
  u += 0x7fffu + ((u >> 16) & 1u);
  return (unsigned short)(u >> 16);
}
__device__ __forceinline__ float bf2f(unsigned short h) {
  union { unsigned int u; float f; } cv; cv.u = ((unsigned int)h) << 16;
  return cv.f;
}
__device__ __forceinline__ float fsig(float x) { return 1.f / (1.f + __expf(-x)); }
__device__ __forceinline__ float ftanh(float x) {
  x = fminf(fmaxf(x, -10.f), 10.f);
  const float e = __expf(2.f * x);
  return (e - 1.f) / (e + 1.f);
}

// ---- device-coherent (sc0 sc1) accesses: bypass the non-coherent per-XCD L2.
__device__ __forceinline__ void store_dword_dc(void* p, unsigned int v) {
  asm volatile("global_store_dword %0, %1, off sc0 sc1" :: "v"(p), "v"(v) : "memory");
}
__device__ __forceinline__ void store_b128_dc(void* p, uint32x4 v) {
  asm volatile("global_store_dwordx4 %0, %1, off sc0 sc1" :: "v"(p), "v"(v) : "memory");
}
__device__ __forceinline__ unsigned int load_dword_dc(const void* p) {
  unsigned int v;
  asm volatile("global_load_dword %0, %1, off sc0 sc1\n\ts_waitcnt vmcnt(0)"
               : "=v"(v) : "v"(p) : "memory");
  return v;
}
// non-temporal fp32 store: streaming hint -> don't retain in caches (no L3 thrash)
__device__ __forceinline__ void store_dword_nt(void* p, float f) {
  union { float f; unsigned int u; } cv; cv.f = f;
  asm volatile("global_store_dword %0, %1, off nt" :: "v"(p), "v"(cv.u) : "memory");
}

// async global->LDS, 16B per lane (wave-uniform LDS base + lane*16)
__device__ __forceinline__ void gload16(const void* g, void* l) {
  __builtin_amdgcn_global_load_lds(
      (const __attribute__((address_space(1))) unsigned int*)g,
      (__attribute__((address_space(3))) unsigned int*)l, 16, 0, 0);
}

// ---------------- elementwise / init kernels ----------------

__global__ void k_cast4(const float4* __restrict__ s, ushort4* __restrict__ d, int n4) {
  int i = blockIdx.x * blockDim.x + threadIdx.x;
  const int st = gridDim.x * blockDim.x;
  for (; i < n4; i += st) {
    const float4 f = s[i];
    ushort4 v;
    v.x = bfbits(f.x); v.y = bfbits(f.y); v.z = bfbits(f.z); v.w = bfbits(f.w);
    d[i] = v;
  }
}

__global__ void k_bias(const float* __restrict__ a, const float* __restrict__ b,
                       float* __restrict__ o, int n) {
  const int i = blockIdx.x * blockDim.x + threadIdx.x;
  if (i < n) o[i] = a[i] + b[i];
}

// X[m][e] = bf16(embed[captions[b][t]][e]), m = t*64+b (t<63); pad rows -> 0
__global__ void k_gather(const float* __restrict__ embed, const int* __restrict__ caps,
                         unsigned short* __restrict__ X) {
  const int i = blockIdx.x * 256 + threadIdx.x;   // 2048 blocks * 256 = MPAD*E_/4 exact
  const int m = i >> 7, e4 = i & 127;             // 128 float4 per row
  ushort4 v;
  if (m < MROWS) {
    const int t = m >> 6, b = m & 63;
    const int idx = caps[b * T_ + t];
    const float4 f = ((const float4*)embed)[(long)idx * (E_ / 4) + e4];
    v.x = bfbits(f.x); v.y = bfbits(f.y); v.z = bfbits(f.z); v.w = bfbits(f.w);
  } else {
    v = make_ushort4(0, 0, 0, 0);
  }
  ((ushort4*)X)[i] = v;
}

// h0/h1 initial slots (bf16) + private fp32 copies of c0/c1 + zero (padded) flags
__global__ void k_init(const float* __restrict__ hidden, const float* __restrict__ cell,
                       unsigned short* __restrict__ H0, unsigned short* __restrict__ H1,
                       float* __restrict__ c0, float* __restrict__ c1,
                       unsigned int* __restrict__ flags) {
  const int i = blockIdx.x * 256 + threadIdx.x;   // 256 blocks -> 65536 = B_*H_ exact
  H0[i] = bfbits(hidden[i]);
  H1[i] = bfbits(hidden[B_ * H_ + i]);
  c0[i] = cell[i];
  c1[i] = cell[B_ * H_ + i];
  if (i < 192 * FPAD) flags[i] = 0u;
}

__global__ void k_zeropad(unsigned short* __restrict__ a, unsigned short* __restrict__ b) {
  const int i = blockIdx.x * 256 + threadIdx.x;   // 65536
  a[i] = 0;
  b[i] = 0;
}

__global__ void k_zero_t0(float4* __restrict__ out4) {
  const int i = blockIdx.x * 256 + threadIdx.x;   // 2000 blocks -> 512000 = B_*V_/4 exact
  const int b = i / (V_ / 4), v = i - b * (V_ / 4);
  out4[(long)b * (T_ * V_ / 4) + v] = make_float4(0.f, 0.f, 0.f, 0.f);
}

// ---------------- big GEMM: C(MPADxN) = A(MPADxK) @ Bm(NxK)^T + bias ----------------
// m97 structure: 128x128 tile, BK=32, global_load_lds(16B), 2 barriers/K-step.
// TO_OUT=false: write bf16 C. TO_OUT=true: fp32 scatter to logits with NT stores
// (streaming writes must not evict the L3-resident Wp between M-tile rows).
template <int KDIM, bool TO_OUT>
__global__ __launch_bounds__(256) void k_gemm(
    const unsigned short* __restrict__ A, const unsigned short* __restrict__ Bm,
    const float* __restrict__ bias, unsigned short* __restrict__ Cb,
    float* __restrict__ Cout, int N) {
  __shared__ unsigned short As[128 * 32];
  __shared__ unsigned short Bs[128 * 32];
  const int tid = threadIdx.x;
  const int w = tid >> 6, l = tid & 63;
  const int wm = (w >> 1) * 64, wn = (w & 1) * 64;
  const int lr = l & 15, lk = (l >> 4) * 8;
  const long am0 = (long)blockIdx.y * 128;
  const long bn0 = (long)blockIdx.x * 128;

  const int u0 = tid, u1 = tid + 256;
  const char* gA0 = (const char*)(A + (am0 + (u0 >> 2)) * KDIM) + (u0 & 3) * 16;
  const char* gA1 = (const char*)(A + (am0 + (u1 >> 2)) * KDIM) + (u1 & 3) * 16;
  const char* gB0 = (const char*)(Bm + (bn0 + (u0 >> 2)) * KDIM) + (u0 & 3) * 16;
  const char* gB1 = (const char*)(Bm + (bn0 + (u1 >> 2)) * KDIM) + (u1 & 3) * 16;
  char* lA0 = (char*)As + u0 * 16; char* lA1 = (char*)As + u1 * 16;
  char* lB0 = (char*)Bs + u0 * 16; char* lB1 = (char*)Bs + u1 * 16;

  f32x4 acc[4][4];
  const f32x4 z = {0.f, 0.f, 0.f, 0.f};
  #pragma unroll
  for (int mi = 0; mi < 4; ++mi)
    #pragma unroll
    for (int ni = 0; ni < 4; ++ni) acc[mi][ni] = z;

  for (int k0 = 0; k0 < KDIM; k0 += 32) {
    __syncthreads();
    gload16(gA0 + (long)k0 * 2, lA0);
    gload16(gA1 + (long)k0 * 2, lA1);
    gload16(gB0 + (long)k0 * 2, lB0);
    gload16(gB1 + (long)k0 * 2, lB1);
    __syncthreads();
    bf16x8 af[4], bfr[4];
    #pragma unroll
    for (int mi = 0; mi < 4; ++mi)
      af[mi] = *(const bf16x8*)(As + (wm + mi * 16 + lr) * 32 + lk);
    #pragma unroll
    for (int ni = 0; ni < 4; ++ni)
      bfr[ni] = *(const bf16x8*)(Bs + (wn + ni * 16 + lr) * 32 + lk);
    #pragma unroll
    for (int mi = 0; mi < 4; ++mi)
      #pragma unroll
      for (int ni = 0; ni < 4; ++ni)
        acc[mi][ni] = __builtin_amdgcn_mfma_f32_16x16x32_bf16(af[mi], bfr[ni], acc[mi][ni], 0, 0, 0);
  }

  #pragma unroll
  for (int ni = 0; ni < 4; ++ni) {
    const int n = (int)bn0 + wn + ni * 16 + lr;
    const float bv = bias[n];
    #pragma unroll
    for (int mi = 0; mi < 4; ++mi) {
      #pragma unroll
      for (int r = 0; r < 4; ++r) {
        const int m = (int)am0 + wm + mi * 16 + (l >> 4) * 4 + r;
        const float v = acc[mi][ni][r] + bv;
        if constexpr (TO_OUT) {
          if (m < MROWS) {
            const int t = m >> 6, b = m & 63;
            store_dword_nt(Cout + (long)(b * T_ + t + 1) * V_ + n, v);
          }
        } else {
          Cb[(long)m * N + n] = bfbits(v);
        }
      }
    }
  }
}

// ---------------- fused 2-layer persistent recurrence ----------------
// 192 co-resident blocks (1/CU), two concurrent teams:
//   team-0 = blocks 0..63:   layer-0, 16 j-cols each; stage s computes h0[s+1].
//   team-1 = blocks 64..191: layer-1, 8 j-cols each; stage s computes
//     h1[s] = cell(h1[s-1]@Whh1^T + h0[s]@Wih1^T + b1), one stage behind team-0.
// Cross-XCD protocol: sc0sc1 write-through h stores + per-block flag array.
// Flags are PADDED to one 128B line each (FPAD) so the 192x64 concurrent sc0sc1
// poll streams spread across L3 slices instead of serializing on 1-2 hot lines.
__global__ __launch_bounds__(256) void k_fused(
    const unsigned short* __restrict__ Whh0b,  // [4096][1024] bf16
    const unsigned short* __restrict__ Whh1b,  // [4096][1024] bf16
    const unsigned short* __restrict__ Wih1b,  // [4096][1024] bf16
    const unsigned short* __restrict__ Xp,     // [63][64][4096] bf16 (x-proj + b0)
    unsigned short* __restrict__ H0b,          // [65][64][1024] bf16, slot 0 init
    unsigned short* __restrict__ H1b,          // [65][64][1024] bf16, slot 0 init
    const float* __restrict__ c0i, const float* __restrict__ c1i,
    const float* __restrict__ b1s,             // [4096] f32
    unsigned int* __restrict__ f0,             // [64*FPAD]  zeroed
    unsigned int* __restrict__ f1) {           // [128*FPAD] zeroed
  __shared__ unsigned short Wl[64 * 1024];     // 128 KB
  __shared__ __align__(16) float gs1[4][64][8];  // 8 KB (team-1); aliased by team-0
  unsigned short (*hexch)[16] = (unsigned short (*)[16])gs1;

  const int tid = threadIdx.x;
  const int w = tid >> 6, l = tid & 63;
  const int lcol = l & 15, khi = l >> 4;
  const int bw = w * 16;
  const f32x4 z = {0.f, 0.f, 0.f, 0.f};

  if (blockIdx.x < 64) {
    // ================= TEAM 0 : layer 0 =================
    const int blk = blockIdx.x;
    const int jb = blk << 4;
    for (int u = tid; u < 64 * 128; u += 256) {
      const int rr = u >> 7, cu = u & 127;
      const int g = rr >> 4, jj = rr & 15;
      ((bf16x8*)Wl)[rr * 128 + (cu ^ (rr & 7))] =
          *(const bf16x8*)(Whh0b + (size_t)(g * 1024 + jb + jj) * H_ + cu * 8);
    }
    f32x4 cr;
    #pragma unroll
    for (int r = 0; r < 4; ++r)
      cr[r] = c0i[(size_t)(bw + khi * 4 + r) * H_ + jb + lcol];
    unsigned short pin[16];
    #pragma unroll
    for (int r = 0; r < 4; ++r) {
      const unsigned short* ir = Xp + (size_t)(bw + khi * 4 + r) * G4_ + jb + lcol;
      pin[r * 4 + 0] = ir[0];
      pin[r * 4 + 1] = ir[H_];
      pin[r * 4 + 2] = ir[2 * H_];
      pin[r * 4 + 3] = ir[3 * H_];
    }
    __syncthreads();

    for (int s = 0; s < TS_; ++s) {
      if (s > 0) {
        if (tid < 64)
          while (load_dword_dc(&f0[tid << 5]) < (unsigned)s) {}
        __syncthreads();
      }
      f32x4 a0, a1, a2, a3;
      #pragma unroll
      for (int r = 0; r < 4; ++r) {
        a0[r] = bf2f(pin[r * 4 + 0]);
        a1[r] = bf2f(pin[r * 4 + 1]);
        a2[r] = bf2f(pin[r * 4 + 2]);
        a3[r] = bf2f(pin[r * 4 + 3]);
      }
      const unsigned short* hrow = H0b + (size_t)s * BH + (size_t)(bw + lcol) * H_ + khi * 8;
      #pragma unroll 8
      for (int kk = 0; kk < 32; ++kk) {
        const bf16x8 av = *(const bf16x8*)(hrow + kk * 32);
        const int un = (kk * 4 + khi) ^ (lcol & 7);
        const bf16x8 b0 = ((const bf16x8*)Wl)[(0 * 16 + lcol) * 128 + un];
        const bf16x8 b1 = ((const bf16x8*)Wl)[(1 * 16 + lcol) * 128 + un];
        const bf16x8 b2 = ((const bf16x8*)Wl)[(2 * 16 + lcol) * 128 + un];
        const bf16x8 b3 = ((const bf16x8*)Wl)[(3 * 16 + lcol) * 128 + un];
        a0 = __builtin_amdgcn_mfma_f32_16x16x32_bf16(av, b0, a0, 0, 0, 0);
        a1 = __builtin_amdgcn_mfma_f32_16x16x32_bf16(av, b1, a1, 0, 0, 0);
        a2 = __builtin_amdgcn_mfma_f32_16x16x32_bf16(av, b2, a2, 0, 0, 0);
        a3 = __builtin_amdgcn_mfma_f32_16x16x32_bf16(av, b3, a3, 0, 0, 0);
      }
      #pragma unroll
      for (int r = 0; r < 4; ++r) {
        const float gi = fsig(a0[r]);
        const float gf = fsig(a1[r]);
        const float gg = ftanh(a2[r]);
        const float go = fsig(a3[r]);
        cr[r] = gf * cr[r] + gi * gg;
        hexch[bw + khi * 4 + r][lcol] = bfbits(go * ftanh(cr[r]));
      }
      if (s + 1 < TS_) {
        const unsigned short* inb = Xp + (size_t)(s + 1) * (B_ * G4_);
        #pragma unroll
        for (int r = 0; r < 4; ++r) {
          const unsigned short* ir = inb + (size_t)(bw + khi * 4 + r) * G4_ + jb + lcol;
          pin[r * 4 + 0] = ir[0];
          pin[r * 4 + 1] = ir[H_];
          pin[r * 4 + 2] = ir[2 * H_];
          pin[r * 4 + 3] = ir[3 * H_];
        }
      }
      __syncthreads();                       // hexch complete
      if (tid < 128) {                       // coalesced 16B device-coherent stores
        const int b = tid >> 1, hf = tid & 1;
        const uint32x4 v = *(const uint32x4*)&hexch[b][hf * 8];
        store_b128_dc(H0b + (size_t)(s + 1) * BH + (size_t)b * H_ + jb + hf * 8, v);
      }
      __syncthreads();                       // drain stores (per-wave vmcnt)
      if (tid == 0) store_dword_dc(&f0[blk << 5], (unsigned)(s + 1));
    }
  } else {
    // ================= TEAM 1 : layer 1 =================
    const int blk1 = blockIdx.x - 64;
    const int jb1 = blk1 << 3;
    for (int u = tid; u < 64 * 128; u += 256) {
      const int pr = u >> 7, cu = u & 127;
      const int prl = pr & 31, tt = prl >> 4, lr_ = prl & 15;
      const int g = tt * 2 + (lr_ >> 3), jj = lr_ & 7;
      const unsigned short* src =
          ((pr >> 5) ? Wih1b : Whh1b) + (size_t)(g * 1024 + jb1 + jj) * H_ + cu * 8;
      ((bf16x8*)Wl)[pr * 128 + (cu ^ (pr & 7))] = *(const bf16x8*)src;
    }
    const int bb = tid >> 2;
    const int j0 = (tid * 2) & 7;
    float cA = c1i[(size_t)bb * H_ + jb1 + j0];
    float cB = c1i[(size_t)bb * H_ + jb1 + j0 + 1];
    float biA[4], biB[4];
    #pragma unroll
    for (int g = 0; g < 4; ++g) {
      biA[g] = b1s[g * 1024 + jb1 + j0];
      biB[g] = b1s[g * 1024 + jb1 + j0 + 1];
    }
    __syncthreads();

    for (int s = 1; s <= TS_; ++s) {
      {  // poll: h0[s] ready (f0 >= s) and h1[s-1] ready (f1 >= s-1)
        const unsigned t0 = (unsigned)s, t1 = (unsigned)(s - 1);
        if (tid < 64) {
          while (load_dword_dc(&f0[tid << 5]) < t0) {}
        } else if (tid < 192) {
          while (load_dword_dc(&f1[(tid - 64) << 5]) < t1) {}
        }
        __syncthreads();
      }
      f32x4 ac0 = z, ac1 = z;
      const unsigned short* a1p = H1b + (size_t)(s - 1) * BH + (size_t)(bw + lcol) * H_ + khi * 8;
      const unsigned short* a0p = H0b + (size_t)s * BH + (size_t)(bw + lcol) * H_ + khi * 8;
      #pragma unroll 8
      for (int kk = 0; kk < 32; ++kk) {
        const bf16x8 av = *(const bf16x8*)(a1p + kk * 32);
        const int un = (kk * 4 + khi) ^ (lcol & 7);
        const bf16x8 b0 = ((const bf16x8*)Wl)[(0 + lcol) * 128 + un];
        const bf16x8 b1 = ((const bf16x8*)Wl)[(16 + lcol) * 128 + un];
        ac0 = __builtin_amdgcn_mfma_f32_16x16x32_bf16(av, b0, ac0, 0, 0, 0);
        ac1 = __builtin_amdgcn_mfma_f32_16x16x32_bf16(av, b1, ac1, 0, 0, 0);
      }
      #pragma unroll 8
      for (int kk = 0; kk < 32; ++kk) {
        const bf16x8 av = *(const bf16x8*)(a0p + kk * 32);
        const int un = (kk * 4 + khi) ^ (lcol & 7);
        const bf16x8 b0 = ((const bf16x8*)Wl)[(32 + lcol) * 128 + un];
        const bf16x8 b1 = ((const bf16x8*)Wl)[(48 + lcol) * 128 + un];
        ac0 = __builtin_amdgcn_mfma_f32_16x16x32_bf16(av, b0, ac0, 0, 0, 0);
        ac1 = __builtin_amdgcn_mfma_f32_16x16x32_bf16(av, b1, ac1, 0, 0, 0);
      }
      #pragma unroll
      for (int r = 0; r < 4; ++r) {
        const int b = bw + khi * 4 + r;
        gs1[lcol >> 3][b][lcol & 7] = ac0[r];
        gs1[2 + (lcol >> 3)][b][lcol & 7] = ac1[r];
      }
      __syncthreads();
      {
        const float giA = fsig(gs1[0][bb][j0] + biA[0]);
        const float gfA = fsig(gs1[1][bb][j0] + biA[1]);
        const float ggA = ftanh(gs1[2][bb][j0] + biA[2]);
        const float goA = fsig(gs1[3][bb][j0] + biA[3]);
        cA = gfA * cA + giA * ggA;
        const unsigned short hA = bfbits(goA * ftanh(cA));
        const float giB = fsig(gs1[0][bb][j0 + 1] + biB[0]);
        const float gfB = fsig(gs1[1][bb][j0 + 1] + biB[1]);
        const float ggB = ftanh(gs1[2][bb][j0 + 1] + biB[2]);
        const float goB = fsig(gs1[3][bb][j0 + 1] + biB[3]);
        cB = gfB * cB + giB * ggB;
        const unsigned short hB = bfbits(goB * ftanh(cB));
        const unsigned int hv = ((unsigned int)hB << 16) | hA;
        store_dword_dc(H1b + (size_t)s * BH + (size_t)bb * H_ + jb1 + j0, hv);
      }
      __syncthreads();                       // drain stores + gs1 WAR protection
      if (tid == 0) store_dword_dc(&f1[blk1 << 5], (unsigned)s);
    }
  }
}

// ---------------- launch ----------------

extern "C" void kernel_launch(void* const* d_in, const int* in_sizes, int n_in,
                              void* d_out, int out_size, void* d_ws, size_t ws_size,
                              hipStream_t stream) {
  (void)in_sizes; (void)n_in; (void)out_size; (void)ws_size;
  const float* hidden = (const float*)d_in[0];
  const float* cell   = (const float*)d_in[1];
  const int*   caps   = (const int*)d_in[2];
  const float* embed  = (const float*)d_in[3];
  const float* Wih0   = (const float*)d_in[4];
  const float* Whh0   = (const float*)d_in[5];
  const float* bih0   = (const float*)d_in[6];
  const float* bhh0   = (const float*)d_in[7];
  const float* Wih1   = (const float*)d_in[8];
  const float* Whh1   = (const float*)d_in[9];
  const float* bih1   = (const float*)d_in[10];
  const float* bhh1   = (const float*)d_in[11];
  const float* Wp     = (const float*)d_in[12];
  const float* bp     = (const float*)d_in[13];
  float* out = (float*)d_out;

  // workspace layout (~210 MB)
  char* p = (char*)d_ws;
  auto alloc = [&](size_t bytes) { char* r = p; p += (bytes + 255) & ~(size_t)255; return r; };
  unsigned short* Xbf   = (unsigned short*)alloc((size_t)MPAD * E_ * 2);
  unsigned short* Wih0b = (unsigned short*)alloc((size_t)G4_ * E_ * 2);
  unsigned short* Whh0b = (unsigned short*)alloc((size_t)G4_ * H_ * 2);
  unsigned short* Wih1b = (unsigned short*)alloc((size_t)G4_ * H_ * 2);
  unsigned short* Whh1b = (unsigned short*)alloc((size_t)G4_ * H_ * 2);
  unsigned short* Wpb   = (unsigned short*)alloc((size_t)V_ * H_ * 2);
  unsigned short* Xp    = (unsigned short*)alloc((size_t)MPAD * G4_ * 2);
  unsigned short* H0    = (unsigned short*)alloc((size_t)(MPAD + B_) * H_ * 2);  // slots 0..64
  unsigned short* H1    = (unsigned short*)alloc((size_t)(MPAD + B_) * H_ * 2);
  float* c0  = (float*)alloc((size_t)B_ * H_ * 4);
  float* c1  = (float*)alloc((size_t)B_ * H_ * 4);
  float* b0s = (float*)alloc((size_t)G4_ * 4);
  float* b1s = (float*)alloc((size_t)G4_ * 4);
  unsigned int* cbar = (unsigned int*)alloc((size_t)192 * FPAD * 4);  // f0[64] | f1[128], padded

  k_cast4<<<2048, 256, 0, stream>>>((const float4*)Wih0, (ushort4*)Wih0b, G4_ * E_ / 4);
  k_cast4<<<2048, 256, 0, stream>>>((const float4*)Whh0, (ushort4*)Whh0b, G4_ * H_ / 4);
  k_cast4<<<2048, 256, 0, stream>>>((const float4*)Wih1, (ushort4*)Wih1b, G4_ * H_ / 4);
  k_cast4<<<2048, 256, 0, stream>>>((const float4*)Whh1, (ushort4*)Whh1b, G4_ * H_ / 4);
  k_cast4<<<4096, 256, 0, stream>>>((const float4*)Wp,   (ushort4*)Wpb,   V_ * H_ / 4);
  k_bias<<<16, 256, 0, stream>>>(bih0, bhh0, b0s, G4_);
  k_bias<<<16, 256, 0, stream>>>(bih1, bhh1, b1s, G4_);
  k_gather<<<2048, 256, 0, stream>>>(embed, caps, Xbf);
  k_init<<<256, 256, 0, stream>>>(hidden, cell, H0, H1, c0, c1, cbar);
  k_zeropad<<<256, 256, 0, stream>>>(H0 + (size_t)MPAD * H_, H1 + (size_t)MPAD * H_);
  k_zero_t0<<<2000, 256, 0, stream>>>((float4*)out);

  // GEMM1: Xp = X @ W_ih0^T + b0   (M=4096, N=4096, K=512)
  k_gemm<512, false><<<dim3(32, 32), 256, 0, stream>>>(Xbf, Wih0b, b0s, Xp, nullptr, G4_);

  // fused 2-layer recurrence (192 co-resident blocks, 63 pipelined stages)
  k_fused<<<192, 256, 0, stream>>>(Whh0b, Whh1b, Wih1b, Xp, H0, H1, c0, c1, b1s,
                                   cbar, cbar + 64 * FPAD);

  // GEMM3: logits = H1[1..63] @ Wp^T + bp -> out[:,1:,:]   (M=4096(4032), N=32000, K=1024)
  k_gemm<1024, true><<<dim3(250, 32), 256, 0, stream>>>(H1 + (size_t)B_ * H_, Wpb, bp, nullptr, out, V_);
}